// Round 7
// baseline (486.894 us; speedup 1.0000x reference)
//
#include <hip/hip_runtime.h>

// ---------------- problem constants ----------------
#define NN    10000          // nodes
#define FIN   2000           // input features
#define NH    10             // heads
#define C1    128            // layer-1 out channels per head
#define C2    64             // layer-2 out channels per head
#define HC1   1280           // NH*C1
#define HC2   640            // NH*C2
#define MP    10240          // nodes padded to 256*40 (BM=256 tiles, XCD swizzle needs 40 m-tiles)
#define K1P   2016           // FIN padded to 32 multiple (63*32)

typedef _Float16 f16x8 __attribute__((ext_vector_type(8)));
typedef _Float16 f16x4 __attribute__((ext_vector_type(4)));
typedef _Float16 f16x2 __attribute__((ext_vector_type(2)));
typedef float    f32x4 __attribute__((ext_vector_type(4)));

// ---------------- fp32 -> fp16 cast + pad, float4-vectorized ----------------
__global__ void k_cast_pad4(const float* __restrict__ src, _Float16* __restrict__ dst,
                            int R, int C4, int Cp4) {
    int idx = blockIdx.x * 256 + threadIdx.x;
    int total = MP * Cp4;
    if (idx >= total) return;
    int r = idx / Cp4, c = idx - r * Cp4;
    float4 v = make_float4(0.f, 0.f, 0.f, 0.f);
    if (r < R && c < C4) v = *(const float4*)(src + (long)r * (C4 * 4) + 4 * c);
    f16x4 o = {(_Float16)v.x, (_Float16)v.y, (_Float16)v.z, (_Float16)v.w};
    *(f16x4*)(dst + (long)r * (Cp4 * 4) + 4 * c) = o;
}

// ---------------- zero fp16 pad rows ----------------
__global__ void k_zero_f16(_Float16* __restrict__ p, int count) {
    int i = blockIdx.x * 256 + threadIdx.x;
    if (i < count) p[i] = (_Float16)0.f;
}

// ---------------- W [K][N] -> Wt fp16 [N][Kpad] (zero k-pad) ----------------
__global__ void k_transpose_W(const float* __restrict__ W, _Float16* __restrict__ Wt,
                              int K, int N, int Kpad) {
    __shared__ float tile[32][33];
    int tx = threadIdx.x & 31;
    int ty = threadIdx.x >> 5;           // 0..7
    int kbase = blockIdx.x * 32;
    int nbase = blockIdx.y * 32;
#pragma unroll
    for (int i = 0; i < 4; i++) {
        int k = kbase + ty + i * 8;
        float v = (k < K) ? W[(long)k * N + nbase + tx] : 0.0f;
        tile[ty + i * 8][tx] = v;
    }
    __syncthreads();
#pragma unroll
    for (int i = 0; i < 4; i++) {
        int n = nbase + ty + i * 8;
        Wt[(long)n * Kpad + kbase + tx] = (_Float16)tile[tx][ty + i * 8];
    }
}

// ---------------- async global->LDS helper ----------------
__device__ __forceinline__ void gl2lds16(const void* g, void* l) {
    __builtin_amdgcn_global_load_lds((const __attribute__((address_space(1))) void*)g,
                                     (__attribute__((address_space(3))) void*)l, 16, 0, 0);
}

// s_waitcnt immediates (gfx9 encoding: vmcnt[3:0] | expcnt<<4 | lgkmcnt<<8 | vmcnt[5:4]<<14)
#define WAITCNT_VM6  0x0F76   // vmcnt<=6 (one 6-load stage may remain in flight)
#define WAITCNT_VM0  0x0F70   // vmcnt==0

// ---------------- fp16 MFMA GEMM: C[MpxN](fp16) = A[MpxK] * Bt[NxK]^T ----------------
// BM=256 x BN=128, 4 waves (2x2), wave tile 128x64. Tri-buffered LDS with raw
// s_barrier + s_waitcnt vmcnt(6) (k+1 staging stays in flight across barriers).
// Operand-swapped MFMA -> lane holds 4 consecutive C columns -> packed stores.
__global__ __launch_bounds__(256, 2) void k_gemm(const _Float16* __restrict__ A,
                                                 const _Float16* __restrict__ Bt,
                                                 _Float16* __restrict__ C, int K, int N,
                                                 int NTN) {
    __shared__ char smem[73728] __attribute__((aligned(16)));
    _Float16* As = (_Float16*)smem;             // 3 x 8192 fp16 (16KB each)
    _Float16* Bs = (_Float16*)(smem + 49152);   // 3 x 4096 fp16 (8KB each)

    int bid = blockIdx.x;
    int r = bid & 7, qb = bid >> 3;
    int n_t = qb % NTN;
    int m_t = r + 8 * (qb / NTN);
    int m0 = m_t * 256;
    int n0 = n_t * 128;
    int t = threadIdx.x;
    int lane = t & 63, wave = t >> 6;
    int wr = wave >> 1, wc = wave & 1;
    int lrow = lane & 15, q = lane >> 4;

    f32x4 acc[8][4] = {};

    int sA[4], sB[2];
#pragma unroll
    for (int i = 0; i < 4; i++) sA[i] = t + 256 * i;
#pragma unroll
    for (int i = 0; i < 2; i++) sB[i] = t + 256 * i;
    const _Float16* Ar[4];
    const _Float16* Br[2];
#pragma unroll
    for (int i = 0; i < 4; i++) {
        int row = sA[i] >> 2, gq = (sA[i] & 3) ^ ((sA[i] >> 3) & 3);
        Ar[i] = A + (long)(m0 + row) * K + gq * 8;
    }
#pragma unroll
    for (int i = 0; i < 2; i++) {
        int row = sB[i] >> 2, gq = (sB[i] & 3) ^ ((sB[i] >> 3) & 3);
        Br[i] = Bt + (long)(n0 + row) * K + gq * 8;
    }

    int aoff[8], boff[4];
#pragma unroll
    for (int i = 0; i < 8; i++) {
        int rowa = wr * 128 + i * 16 + lrow;
        aoff[i] = rowa * 32 + ((q ^ ((rowa >> 1) & 3)) << 3);
    }
#pragma unroll
    for (int i = 0; i < 4; i++) {
        int rowb = wc * 64 + i * 16 + lrow;
        boff[i] = rowb * 32 + ((q ^ ((rowb >> 1) & 3)) << 3);
    }

    auto stage = [&](int it, int buf) {
        int k0 = it << 5;
#pragma unroll
        for (int i = 0; i < 4; i++) gl2lds16(Ar[i] + k0, &As[buf * 8192 + sA[i] * 8]);
#pragma unroll
        for (int i = 0; i < 2; i++) gl2lds16(Br[i] + k0, &Bs[buf * 4096 + sB[i] * 8]);
    };

    int nk = K >> 5;
    stage(0, 0);
    stage(1, 1);
    int cur = 0;
    for (int it = 0; it < nk; it++) {
        if (it + 1 < nk) __builtin_amdgcn_s_waitcnt(WAITCNT_VM6);
        else             __builtin_amdgcn_s_waitcnt(WAITCNT_VM0);
        __builtin_amdgcn_s_barrier();
        int nxt = cur + 2; if (nxt >= 3) nxt -= 3;
        if (it + 2 < nk) stage(it + 2, nxt);

        f16x8 af[8], bf[4];
#pragma unroll
        for (int i = 0; i < 8; i++) af[i] = *(const f16x8*)&As[cur * 8192 + aoff[i]];
#pragma unroll
        for (int i = 0; i < 4; i++) bf[i] = *(const f16x8*)&Bs[cur * 4096 + boff[i]];
#pragma unroll
        for (int mt = 0; mt < 8; mt++)
#pragma unroll
            for (int nt = 0; nt < 4; nt++)
                acc[mt][nt] = __builtin_amdgcn_mfma_f32_16x16x32_f16(bf[nt], af[mt], acc[mt][nt], 0, 0, 0);
        cur = (cur + 1 == 3) ? 0 : cur + 1;
    }

#pragma unroll
    for (int mt = 0; mt < 8; mt++) {
        int m = m0 + wr * 128 + mt * 16 + lrow;
#pragma unroll
        for (int nt = 0; nt < 4; nt++) {
            int n = n0 + wc * 64 + nt * 16 + q * 4;
            f16x4 o = {(_Float16)acc[mt][nt][0], (_Float16)acc[mt][nt][1],
                       (_Float16)acc[mt][nt][2], (_Float16)acc[mt][nt][3]};
            *(f16x4*)(C + (long)m * N + n) = o;
        }
    }
}

// ---------------- CSR build ----------------
__global__ void k_csr_count(const int* __restrict__ ei, int* counts, int E) {
    int e = blockIdx.x * 256 + threadIdx.x;
    if (e < E) atomicAdd(&counts[ei[E + e]], 1);
}
// exclusive scan of (counts[i] + 1): the +1 is the self-loop
__global__ void k_scan(const int* __restrict__ counts, int* rowptr, int* cursor, int n) {
    __shared__ int s[1024];
    int t = threadIdx.x;
    int running = 0;
    for (int base = 0; base < n; base += 1024) {
        int i = base + t;
        int v = (i < n) ? (counts[i] + 1) : 0;
        s[t] = v;
        __syncthreads();
        for (int off = 1; off < 1024; off <<= 1) {
            int add = (t >= off) ? s[t - off] : 0;
            __syncthreads();
            s[t] += add;
            __syncthreads();
        }
        if (i < n) { int ex = running + s[t] - v; rowptr[i] = ex; cursor[i] = ex; }
        int tot = s[1023];
        __syncthreads();
        running += tot;
    }
    if (t == 0) rowptr[n] = running;
}
__global__ void k_csr_fill(const int* __restrict__ ei, int* cursor, int* colidx, int E, int n) {
    int i = blockIdx.x * 256 + threadIdx.x;
    if (i >= E + n) return;
    int s, d;
    if (i < E) { s = ei[i]; d = ei[E + i]; }
    else       { s = i - E; d = i - E; }
    int pos = atomicAdd(&cursor[d], 1);
    colidx[pos] = s;
}

// ---------------- per-node logits, TRANSPOSED out: asT/adT [NH][NN] ----------------
__global__ void k_alpha(const _Float16* __restrict__ hpre, const float* __restrict__ asrc,
                        const float* __restrict__ adst, float* asT, float* adT, int C) {
    int wave = threadIdx.x >> 6, lane = threadIdx.x & 63;
    int n = blockIdx.x;
    for (int h = wave; h < NH; h += 4) {
        float sv = 0.f, dv = 0.f;
        for (int c = lane; c < C; c += 64) {
            float hv = (float)hpre[(long)n * NH * C + h * C + c];
            sv += hv * asrc[h * C + c];
            dv += hv * adst[h * C + c];
        }
        for (int m = 32; m; m >>= 1) { sv += __shfl_xor(sv, m); dv += __shfl_xor(dv, m); }
        if (lane == 0) { asT[h * NN + n] = sv; adT[h * NN + n] = dv; }
    }
}

// ---------------- layer-1: fused softmax + per-head aggregation ----------------
// block = (head, node), 64 threads (1 wave). Per-head h1pre slice = 2.56MB ->
// L2-resident per XCD (head-major block order keeps it hot). Softmax in-wave,
// alpha/src broadcast by shuffle; lane owns 2 channels (f16x2 gather).
__global__ __launch_bounds__(64) void k_agg1h(const int* __restrict__ rowptr,
                                              const int* __restrict__ colidx,
                                              const float* __restrict__ asT,
                                              const float* __restrict__ adT,
                                              const _Float16* __restrict__ h,
                                              const float* __restrict__ bias,
                                              _Float16* __restrict__ A2) {
    int bid = blockIdx.x;
    int hd = bid / NN;                 // slow-varying -> same-head blocks cluster in time
    int n  = bid - hd * NN;
    int lane = threadIdx.x;
    int k0 = rowptr[n], deg = rowptr[n + 1] - k0;
    float adv = adT[hd * NN + n];
    float a0 = 0.f, a1 = 0.f;
    const _Float16* hb = h + (long)hd * C1 + 2 * lane;

    if (deg <= 64) {
        int src = (lane < deg) ? colidx[k0 + lane] : 0;
        float e = -1e30f;
        if (lane < deg) {
            e = asT[hd * NN + src] + adv;
            e = e > 0.f ? e : 0.2f * e;
        }
        float mx = e;
        for (int m = 32; m; m >>= 1) mx = fmaxf(mx, __shfl_xor(mx, m));
        float ex = (lane < deg) ? __expf(e - mx) : 0.f;
        float sum = ex;
        for (int m = 32; m; m >>= 1) sum += __shfl_xor(sum, m);
        float alpha = ex / (sum + 1e-16f);
        for (int j = 0; j < deg; j++) {
            float a = __shfl(alpha, j);
            int s  = __shfl(src, j);
            f16x2 v = *(const f16x2*)(hb + (long)s * HC1);
            a0 += a * (float)v[0];
            a1 += a * (float)v[1];
        }
    } else {                            // generic fallback (deg>64: absent at lambda~16)
        float mx = -1e30f;
        for (int j = lane; j < deg; j += 64) {
            float e = asT[hd * NN + colidx[k0 + j]] + adv;
            e = e > 0.f ? e : 0.2f * e;
            mx = fmaxf(mx, e);
        }
        for (int m = 32; m; m >>= 1) mx = fmaxf(mx, __shfl_xor(mx, m));
        float sum = 0.f;
        for (int j = lane; j < deg; j += 64) {
            float e = asT[hd * NN + colidx[k0 + j]] + adv;
            e = e > 0.f ? e : 0.2f * e;
            sum += __expf(e - mx);
        }
        for (int m = 32; m; m >>= 1) sum += __shfl_xor(sum, m);
        float inv = 1.0f / (sum + 1e-16f);
        for (int j0 = 0; j0 < deg; j0 += 64) {
            int jn = min(64, deg - j0);
            int s = (lane < jn) ? colidx[k0 + j0 + lane] : 0;
            float al = 0.f;
            if (lane < jn) {
                float e = asT[hd * NN + s] + adv;
                e = e > 0.f ? e : 0.2f * e;
                al = __expf(e - mx) * inv;
            }
            for (int j = 0; j < jn; j++) {
                float a = __shfl(al, j);
                int ss = __shfl(s, j);
                f16x2 v = *(const f16x2*)(hb + (long)ss * HC1);
                a0 += a * (float)v[0];
                a1 += a * (float)v[1];
            }
        }
    }
    float x0 = a0 + bias[hd * C1 + 2 * lane];
    float x1 = a1 + bias[hd * C1 + 2 * lane + 1];
    f16x2 o = {(_Float16)(x0 > 0.f ? x0 : 0.f), (_Float16)(x1 > 0.f ? x1 : 0.f)};
    *(f16x2*)(A2 + (long)n * HC1 + hd * C1 + 2 * lane) = o;
}

// ---------------- layer-2: fused softmax + aggregation + head mean ----------------
// block per node, 320 threads = 10 head-groups of 32 lanes (width-32 shuffles).
__global__ __launch_bounds__(320) void k_agg2(const int* __restrict__ rowptr,
                                              const int* __restrict__ colidx,
                                              const float* __restrict__ asT,
                                              const float* __restrict__ adT,
                                              const _Float16* __restrict__ h,
                                              const float* __restrict__ bias,
                                              float* __restrict__ out) {
    __shared__ float facc[HC2];
    int n = blockIdx.x, t = threadIdx.x;
    int hd = t >> 5, l = t & 31;
    int k0 = rowptr[n], deg = rowptr[n + 1] - k0;
    float adv = adT[hd * NN + n];
    float a0 = 0.f, a1 = 0.f;
    const _Float16* hb = h + (long)hd * C2 + 2 * l;

    if (deg <= 32) {
        int src = (l < deg) ? colidx[k0 + l] : 0;
        float e = -1e30f;
        if (l < deg) {
            e = asT[hd * NN + src] + adv;
            e = e > 0.f ? e : 0.2f * e;
        }
        float mx = e;
        for (int m = 16; m; m >>= 1) mx = fmaxf(mx, __shfl_xor(mx, m, 32));
        float ex = (l < deg) ? __expf(e - mx) : 0.f;
        float sum = ex;
        for (int m = 16; m; m >>= 1) sum += __shfl_xor(sum, m, 32);
        float alpha = ex / (sum + 1e-16f);
        for (int j = 0; j < deg; j++) {
            float a = __shfl(alpha, j, 32);
            int s  = __shfl(src, j, 32);
            f16x2 v = *(const f16x2*)(hb + (long)s * HC2);
            a0 += a * (float)v[0];
            a1 += a * (float)v[1];
        }
    } else {
        float mx = -1e30f;
        for (int j = l; j < deg; j += 32) {
            float e = asT[hd * NN + colidx[k0 + j]] + adv;
            e = e > 0.f ? e : 0.2f * e;
            mx = fmaxf(mx, e);
        }
        for (int m = 16; m; m >>= 1) mx = fmaxf(mx, __shfl_xor(mx, m, 32));
        float sum = 0.f;
        for (int j = l; j < deg; j += 32) {
            float e = asT[hd * NN + colidx[k0 + j]] + adv;
            e = e > 0.f ? e : 0.2f * e;
            sum += __expf(e - mx);
        }
        for (int m = 16; m; m >>= 1) sum += __shfl_xor(sum, m, 32);
        float inv = 1.0f / (sum + 1e-16f);
        for (int j0 = 0; j0 < deg; j0 += 32) {
            int jn = min(32, deg - j0);
            int s = (l < jn) ? colidx[k0 + j0 + l] : 0;
            float al = 0.f;
            if (l < jn) {
                float e = asT[hd * NN + s] + adv;
                e = e > 0.f ? e : 0.2f * e;
                al = __expf(e - mx) * inv;
            }
            for (int j = 0; j < jn; j++) {
                float a = __shfl(al, j, 32);
                int ss = __shfl(s, j, 32);
                f16x2 v = *(const f16x2*)(hb + (long)ss * HC2);
                a0 += a * (float)v[0];
                a1 += a * (float)v[1];
            }
        }
    }
    facc[hd * C2 + 2 * l] = a0;
    facc[hd * C2 + 2 * l + 1] = a1;
    __syncthreads();
    if (t < C2) {
        float s = 0.f;
#pragma unroll
        for (int hh = 0; hh < NH; hh++) s += facc[hh * C2 + t];
        s = s * 0.1f + bias[t];
        out[(long)n * C2 + t] = s > 0.f ? s : 0.f;
    }
}

// ---------------- host ----------------
extern "C" void kernel_launch(void* const* d_in, const int* in_sizes, int n_in,
                              void* d_out, int out_size, void* d_ws, size_t ws_size,
                              hipStream_t stream) {
    const float* x      = (const float*)d_in[0];
    const int*   ei     = (const int*)d_in[1];
    const float* W1     = (const float*)d_in[2];
    const float* asrc1  = (const float*)d_in[3];
    const float* adst1  = (const float*)d_in[4];
    const float* b1     = (const float*)d_in[5];
    const float* W2     = (const float*)d_in[6];
    const float* asrc2  = (const float*)d_in[7];
    const float* adst2  = (const float*)d_in[8];
    const float* b2     = (const float*)d_in[9];
    float* out = (float*)d_out;
    const int E  = in_sizes[1] / 2;
    const int EN = E + NN;

    char* base = (char*)d_ws;
    size_t o = 0;
    auto alloc = [&](size_t bytes) { size_t r = o; o += (bytes + 255) & ~(size_t)255; return r; };
    _Float16* A1    = (_Float16*)(base + alloc((size_t)MP * K1P * 2));
    _Float16* W1t   = (_Float16*)(base + alloc((size_t)HC1 * K1P * 2));
    _Float16* A2    = (_Float16*)(base + alloc((size_t)MP * HC1 * 2));
    _Float16* W2t   = (_Float16*)(base + alloc((size_t)HC2 * HC1 * 2));
    _Float16* h1pre = (_Float16*)(base + alloc((size_t)MP * HC1 * 2));
    _Float16* h2pre = (_Float16*)(base + alloc((size_t)MP * HC2 * 2));
    float* asT1     = (float*)(base + alloc((size_t)NN * NH * 4));
    float* adT1     = (float*)(base + alloc((size_t)NN * NH * 4));
    float* asT2     = (float*)(base + alloc((size_t)NN * NH * 4));
    float* adT2     = (float*)(base + alloc((size_t)NN * NH * 4));
    int* counts     = (int*)(base + alloc((size_t)(NN + 1) * 4));
    int* rowptr     = (int*)(base + alloc((size_t)(NN + 1) * 4));
    int* cursor     = (int*)(base + alloc((size_t)(NN + 1) * 4));
    int* colidx     = (int*)(base + alloc((size_t)EN * 4));
    (void)ws_size; (void)n_in; (void)out_size;

    // ---- layer 1 GEMM: h1pre(fp16) = x @ W1 ----
    k_cast_pad4<<<(MP * (K1P / 4) + 255) / 256, 256, 0, stream>>>(x, A1, NN, FIN / 4, K1P / 4);
    k_transpose_W<<<dim3(K1P / 32, HC1 / 32), 256, 0, stream>>>(W1, W1t, FIN, HC1, K1P);
    k_gemm<<<8 * (MP / 256 / 8) * (HC1 / 128), 256, 0, stream>>>(A1, W1t, h1pre, K1P, HC1, HC1 / 128);

    // ---- CSR (shared by both layers) ----
    hipMemsetAsync(counts, 0, (size_t)(NN + 1) * 4, stream);
    k_csr_count<<<(E + 255) / 256, 256, 0, stream>>>(ei, counts, E);
    k_scan<<<1, 1024, 0, stream>>>(counts, rowptr, cursor, NN);
    k_csr_fill<<<(EN + 255) / 256, 256, 0, stream>>>(ei, cursor, colidx, E, NN);

    // ---- layer 1 attention + aggregate (softmax fused, per-head L2 tiling) ----
    k_alpha<<<NN, 256, 0, stream>>>(h1pre, asrc1, adst1, asT1, adT1, C1);
    k_agg1h<<<NH * NN, 64, 0, stream>>>(rowptr, colidx, asT1, adT1, h1pre, b1, A2);
    k_zero_f16<<<((MP - NN) * HC1 + 255) / 256, 256, 0, stream>>>(A2 + (long)NN * HC1, (MP - NN) * HC1);

    // ---- layer 2 GEMM: h2pre(fp16) = A2 @ W2 ----
    k_transpose_W<<<dim3(HC1 / 32, HC2 / 32), 256, 0, stream>>>(W2, W2t, HC1, HC2, HC1);
    k_gemm<<<8 * (MP / 256 / 8) * (HC2 / 128), 256, 0, stream>>>(A2, W2t, h2pre, HC1, HC2, HC2 / 128);

    // ---- layer 2 attention + aggregate (softmax fused) + head mean ----
    k_alpha<<<NN, 256, 0, stream>>>(h2pre, asrc2, adst2, asT2, adT2, C2);
    k_agg2<<<NN, 320, 0, stream>>>(rowptr, colidx, asT2, adT2, h2pre, b2, out);
}

// Round 8
// 432.138 us; speedup vs baseline: 1.1267x; 1.1267x over previous
//
#include <hip/hip_runtime.h>

// ---------------- problem constants ----------------
#define NN    10000          // nodes
#define FIN   2000           // input features
#define NH    10             // heads
#define C1    128            // layer-1 out channels per head
#define C2    64             // layer-2 out channels per head
#define HC1   1280           // NH*C1
#define HC2   640            // NH*C2
#define MP    10240          // nodes padded to 256*40 (BM=256 tiles, XCD swizzle needs 40 m-tiles)
#define K1P   2016           // FIN padded to 32 multiple (63*32)

typedef _Float16 f16x8 __attribute__((ext_vector_type(8)));
typedef _Float16 f16x4 __attribute__((ext_vector_type(4)));
typedef _Float16 f16x2 __attribute__((ext_vector_type(2)));
typedef float    f32x4 __attribute__((ext_vector_type(4)));

__device__ __forceinline__ float leaky(float x) { return x > 0.f ? x : 0.2f * x; }

// ---------------- fp32 -> fp16 cast + pad, float4-vectorized ----------------
__global__ void k_cast_pad4(const float* __restrict__ src, _Float16* __restrict__ dst,
                            int R, int C4, int Cp4) {
    int idx = blockIdx.x * 256 + threadIdx.x;
    int total = MP * Cp4;
    if (idx >= total) return;
    int r = idx / Cp4, c = idx - r * Cp4;
    float4 v = make_float4(0.f, 0.f, 0.f, 0.f);
    if (r < R && c < C4) v = *(const float4*)(src + (long)r * (C4 * 4) + 4 * c);
    f16x4 o = {(_Float16)v.x, (_Float16)v.y, (_Float16)v.z, (_Float16)v.w};
    *(f16x4*)(dst + (long)r * (Cp4 * 4) + 4 * c) = o;
}

// ---------------- W [K][N] -> Wt fp16 [N][Kpad] (zero k-pad) ----------------
__global__ void k_transpose_W(const float* __restrict__ W, _Float16* __restrict__ Wt,
                              int K, int N, int Kpad) {
    __shared__ float tile[32][33];
    int tx = threadIdx.x & 31;
    int ty = threadIdx.x >> 5;           // 0..7
    int kbase = blockIdx.x * 32;
    int nbase = blockIdx.y * 32;
#pragma unroll
    for (int i = 0; i < 4; i++) {
        int k = kbase + ty + i * 8;
        float v = (k < K) ? W[(long)k * N + nbase + tx] : 0.0f;
        tile[ty + i * 8][tx] = v;
    }
    __syncthreads();
#pragma unroll
    for (int i = 0; i < 4; i++) {
        int n = nbase + ty + i * 8;
        Wt[(long)n * Kpad + kbase + tx] = (_Float16)tile[tx][ty + i * 8];
    }
}

// ---------------- async global->LDS helper ----------------
__device__ __forceinline__ void gl2lds16(const void* g, void* l) {
    __builtin_amdgcn_global_load_lds((const __attribute__((address_space(1))) void*)g,
                                     (__attribute__((address_space(3))) void*)l, 16, 0, 0);
}

// s_waitcnt immediates (gfx9 encoding: vmcnt[3:0] | expcnt<<4 | lgkmcnt<<8 | vmcnt[5:4]<<14)
#define WAITCNT_VM6  0x0F76   // vmcnt<=6 (one 6-load stage may remain in flight)
#define WAITCNT_VM0  0x0F70   // vmcnt==0

// ---------------- fp16 MFMA GEMM: C[MpxN](fp16) = A[MpxK] * Bt[NxK]^T ----------------
// BM=256 x BN=128, 4 waves (2x2), wave tile 128x64. Tri-buffered LDS with raw
// s_barrier + s_waitcnt vmcnt(6) (k+1 staging stays in flight across barriers).
// Operand-swapped MFMA -> lane holds 4 consecutive C columns -> packed stores.
__global__ __launch_bounds__(256, 2) void k_gemm(const _Float16* __restrict__ A,
                                                 const _Float16* __restrict__ Bt,
                                                 _Float16* __restrict__ C, int K, int N,
                                                 int NTN) {
    __shared__ char smem[73728] __attribute__((aligned(16)));
    _Float16* As = (_Float16*)smem;             // 3 x 8192 fp16 (16KB each)
    _Float16* Bs = (_Float16*)(smem + 49152);   // 3 x 4096 fp16 (8KB each)

    int bid = blockIdx.x;
    int r = bid & 7, qb = bid >> 3;
    int n_t = qb % NTN;
    int m_t = r + 8 * (qb / NTN);
    int m0 = m_t * 256;
    int n0 = n_t * 128;
    int t = threadIdx.x;
    int lane = t & 63, wave = t >> 6;
    int wr = wave >> 1, wc = wave & 1;
    int lrow = lane & 15, q = lane >> 4;

    f32x4 acc[8][4] = {};

    int sA[4], sB[2];
#pragma unroll
    for (int i = 0; i < 4; i++) sA[i] = t + 256 * i;
#pragma unroll
    for (int i = 0; i < 2; i++) sB[i] = t + 256 * i;
    const _Float16* Ar[4];
    const _Float16* Br[2];
#pragma unroll
    for (int i = 0; i < 4; i++) {
        int row = sA[i] >> 2, gq = (sA[i] & 3) ^ ((sA[i] >> 3) & 3);
        Ar[i] = A + (long)(m0 + row) * K + gq * 8;
    }
#pragma unroll
    for (int i = 0; i < 2; i++) {
        int row = sB[i] >> 2, gq = (sB[i] & 3) ^ ((sB[i] >> 3) & 3);
        Br[i] = Bt + (long)(n0 + row) * K + gq * 8;
    }

    int aoff[8], boff[4];
#pragma unroll
    for (int i = 0; i < 8; i++) {
        int rowa = wr * 128 + i * 16 + lrow;
        aoff[i] = rowa * 32 + ((q ^ ((rowa >> 1) & 3)) << 3);
    }
#pragma unroll
    for (int i = 0; i < 4; i++) {
        int rowb = wc * 64 + i * 16 + lrow;
        boff[i] = rowb * 32 + ((q ^ ((rowb >> 1) & 3)) << 3);
    }

    auto stage = [&](int it, int buf) {
        int k0 = it << 5;
#pragma unroll
        for (int i = 0; i < 4; i++) gl2lds16(Ar[i] + k0, &As[buf * 8192 + sA[i] * 8]);
#pragma unroll
        for (int i = 0; i < 2; i++) gl2lds16(Br[i] + k0, &Bs[buf * 4096 + sB[i] * 8]);
    };

    int nk = K >> 5;
    stage(0, 0);
    stage(1, 1);
    int cur = 0;
    for (int it = 0; it < nk; it++) {
        if (it + 1 < nk) __builtin_amdgcn_s_waitcnt(WAITCNT_VM6);
        else             __builtin_amdgcn_s_waitcnt(WAITCNT_VM0);
        __builtin_amdgcn_s_barrier();
        int nxt = cur + 2; if (nxt >= 3) nxt -= 3;
        if (it + 2 < nk) stage(it + 2, nxt);

        f16x8 af[8], bf[4];
#pragma unroll
        for (int i = 0; i < 8; i++) af[i] = *(const f16x8*)&As[cur * 8192 + aoff[i]];
#pragma unroll
        for (int i = 0; i < 4; i++) bf[i] = *(const f16x8*)&Bs[cur * 4096 + boff[i]];
#pragma unroll
        for (int mt = 0; mt < 8; mt++)
#pragma unroll
            for (int nt = 0; nt < 4; nt++)
                acc[mt][nt] = __builtin_amdgcn_mfma_f32_16x16x32_f16(bf[nt], af[mt], acc[mt][nt], 0, 0, 0);
        cur = (cur + 1 == 3) ? 0 : cur + 1;
    }

#pragma unroll
    for (int mt = 0; mt < 8; mt++) {
        int m = m0 + wr * 128 + mt * 16 + lrow;
#pragma unroll
        for (int nt = 0; nt < 4; nt++) {
            int n = n0 + wc * 64 + nt * 16 + q * 4;
            f16x4 o = {(_Float16)acc[mt][nt][0], (_Float16)acc[mt][nt][1],
                       (_Float16)acc[mt][nt][2], (_Float16)acc[mt][nt][3]};
            *(f16x4*)(C + (long)m * N + n) = o;
        }
    }
}

// ---------------- CSR build ----------------
__global__ void k_csr_count(const int* __restrict__ ei, int* counts, int E) {
    int e = blockIdx.x * 256 + threadIdx.x;
    if (e < E) atomicAdd(&counts[ei[E + e]], 1);
}
// exclusive scan of (counts[i] + 1): the +1 is the self-loop
__global__ void k_scan(const int* __restrict__ counts, int* rowptr, int* cursor, int n) {
    __shared__ int s[1024];
    int t = threadIdx.x;
    int running = 0;
    for (int base = 0; base < n; base += 1024) {
        int i = base + t;
        int v = (i < n) ? (counts[i] + 1) : 0;
        s[t] = v;
        __syncthreads();
        for (int off = 1; off < 1024; off <<= 1) {
            int add = (t >= off) ? s[t - off] : 0;
            __syncthreads();
            s[t] += add;
            __syncthreads();
        }
        if (i < n) { int ex = running + s[t] - v; rowptr[i] = ex; cursor[i] = ex; }
        int tot = s[1023];
        __syncthreads();
        running += tot;
    }
    if (t == 0) rowptr[n] = running;
}
__global__ void k_csr_fill(const int* __restrict__ ei, int* cursor, int* colidx, int E, int n) {
    int i = blockIdx.x * 256 + threadIdx.x;
    if (i >= E + n) return;
    int s, d;
    if (i < E) { s = ei[i]; d = ei[E + i]; }
    else       { s = i - E; d = i - E; }
    int pos = atomicAdd(&cursor[d], 1);
    colidx[pos] = s;
}

// ---------------- per-node logits: as/ad [N][NH] ----------------
__global__ void k_alpha(const _Float16* __restrict__ hpre, const float* __restrict__ asrc,
                        const float* __restrict__ adst, float* as, float* ad, int C) {
    int wave = threadIdx.x >> 6, lane = threadIdx.x & 63;
    int n = blockIdx.x;
    for (int h = wave; h < NH; h += 4) {
        float sv = 0.f, dv = 0.f;
        for (int c = lane; c < C; c += 64) {
            float hv = (float)hpre[(long)n * NH * C + h * C + c];
            sv += hv * asrc[h * C + c];
            dv += hv * adst[h * C + c];
        }
        for (int m = 32; m; m >>= 1) { sv += __shfl_xor(sv, m); dv += __shfl_xor(dv, m); }
        if (lane == 0) { as[n * NH + h] = sv; ad[n * NH + h] = dv; }
    }
}

// ---------------- layer-1: FUSED softmax + wide-row aggregation -> A2 fp16 ----------------
// 320 threads. Softmax phase: wave w (0..4) computes alpha for heads 2w,2w+1
// (logits read as one float2 per src) into LDS. Gather phase: thread t owns
// channels 4t..4t+3 (head = t>>5), f16x4 row gather (R6-proven wide pattern).
// grid = MP: pad rows (n >= NN) write zeros (folds k_zero_f16).
__global__ __launch_bounds__(320) void k_agg1(const int* __restrict__ rowptr,
                                              const int* __restrict__ colidx,
                                              const float* __restrict__ as,
                                              const float* __restrict__ ad,
                                              const _Float16* __restrict__ h,
                                              const float* __restrict__ bias,
                                              _Float16* __restrict__ A2) {
    __shared__ int sidx[64];
    __shared__ float sal[64 * NH];
    int n = blockIdx.x, t = threadIdx.x;
    if (n >= NN) {
        f16x4 z = {(_Float16)0.f, (_Float16)0.f, (_Float16)0.f, (_Float16)0.f};
        *(f16x4*)(A2 + (long)n * HC1 + 4 * t) = z;
        return;
    }
    int k0 = rowptr[n], deg = rowptr[n + 1] - k0;
    int w = t >> 6, lane = t & 63;
    int hd = t >> 5;                       // gather-phase head (4 ch/thread)
    float acc[4] = {0, 0, 0, 0};

    if (deg <= 64) {
        // --- softmax: wave w handles heads 2w, 2w+1 ---
        int src = (lane < deg) ? colidx[k0 + lane] : 0;
        float2 adv = *(const float2*)(ad + n * NH + 2 * w);
        float e0 = -1e30f, e1 = -1e30f;
        if (lane < deg) {
            float2 av = *(const float2*)(as + (long)src * NH + 2 * w);
            e0 = leaky(av.x + adv.x);
            e1 = leaky(av.y + adv.y);
        }
        float m0 = e0, m1 = e1;
        for (int m = 32; m; m >>= 1) {
            m0 = fmaxf(m0, __shfl_xor(m0, m));
            m1 = fmaxf(m1, __shfl_xor(m1, m));
        }
        float x0 = (lane < deg) ? __expf(e0 - m0) : 0.f;
        float x1 = (lane < deg) ? __expf(e1 - m1) : 0.f;
        float s0 = x0, s1 = x1;
        for (int m = 32; m; m >>= 1) {
            s0 += __shfl_xor(s0, m);
            s1 += __shfl_xor(s1, m);
        }
        if (lane < deg) {
            sal[lane * NH + 2 * w]     = x0 / (s0 + 1e-16f);
            sal[lane * NH + 2 * w + 1] = x1 / (s1 + 1e-16f);
            if (w == 0) sidx[lane] = src;
        }
        __syncthreads();
        // --- wide gather ---
        for (int j = 0; j < deg; j++) {
            int src2 = sidx[j];
            float a = sal[j * NH + hd];
            f16x4 v = *(const f16x4*)(h + (long)src2 * HC1 + 4 * t);
            acc[0] += a * (float)v[0];
            acc[1] += a * (float)v[1];
            acc[2] += a * (float)v[2];
            acc[3] += a * (float)v[3];
        }
    } else {
        // --- generic fallback (deg>64: ~never at mean degree 16) ---
        float2 adv = *(const float2*)(ad + n * NH + 2 * w);
        float m0 = -1e30f, m1 = -1e30f;
        for (int j = lane; j < deg; j += 64) {
            float2 av = *(const float2*)(as + (long)colidx[k0 + j] * NH + 2 * w);
            m0 = fmaxf(m0, leaky(av.x + adv.x));
            m1 = fmaxf(m1, leaky(av.y + adv.y));
        }
        for (int m = 32; m; m >>= 1) {
            m0 = fmaxf(m0, __shfl_xor(m0, m));
            m1 = fmaxf(m1, __shfl_xor(m1, m));
        }
        float s0 = 0.f, s1 = 0.f;
        for (int j = lane; j < deg; j += 64) {
            float2 av = *(const float2*)(as + (long)colidx[k0 + j] * NH + 2 * w);
            s0 += __expf(leaky(av.x + adv.x) - m0);
            s1 += __expf(leaky(av.y + adv.y) - m1);
        }
        for (int m = 32; m; m >>= 1) {
            s0 += __shfl_xor(s0, m);
            s1 += __shfl_xor(s1, m);
        }
        float i0 = 1.f / (s0 + 1e-16f), i1 = 1.f / (s1 + 1e-16f);
        for (int c0 = 0; c0 < deg; c0 += 64) {
            int cn = min(64, deg - c0);
            __syncthreads();
            if (lane < cn) {
                int src = colidx[k0 + c0 + lane];
                float2 av = *(const float2*)(as + (long)src * NH + 2 * w);
                sal[lane * NH + 2 * w]     = __expf(leaky(av.x + adv.x) - m0) * i0;
                sal[lane * NH + 2 * w + 1] = __expf(leaky(av.y + adv.y) - m1) * i1;
                if (w == 0) sidx[lane] = src;
            }
            __syncthreads();
            for (int j = 0; j < cn; j++) {
                int src2 = sidx[j];
                float a = sal[j * NH + hd];
                f16x4 v = *(const f16x4*)(h + (long)src2 * HC1 + 4 * t);
                acc[0] += a * (float)v[0];
                acc[1] += a * (float)v[1];
                acc[2] += a * (float)v[2];
                acc[3] += a * (float)v[3];
            }
        }
    }
    f16x4 o;
#pragma unroll
    for (int i = 0; i < 4; i++) {
        float x = acc[i] + bias[4 * t + i];
        o[i] = (_Float16)(x > 0.f ? x : 0.f);
    }
    *(f16x4*)(A2 + (long)n * HC1 + 4 * t) = o;
}

// ---------------- layer-2: FUSED softmax + aggregation + head mean + bias + relu ----------------
// 320 threads: softmax phase as k_agg1; gather: thread t owns channels 2t,2t+1 (head=t>>5).
__global__ __launch_bounds__(320) void k_agg2(const int* __restrict__ rowptr,
                                              const int* __restrict__ colidx,
                                              const float* __restrict__ as,
                                              const float* __restrict__ ad,
                                              const _Float16* __restrict__ h,
                                              const float* __restrict__ bias,
                                              float* __restrict__ out) {
    __shared__ int sidx[64];
    __shared__ float sal[64 * NH];
    __shared__ float facc[HC2];
    int n = blockIdx.x, t = threadIdx.x;
    int k0 = rowptr[n], deg = rowptr[n + 1] - k0;
    int w = t >> 6, lane = t & 63;
    int hd = t >> 5;
    float a0 = 0.f, a1 = 0.f;

    if (deg <= 64) {
        int src = (lane < deg) ? colidx[k0 + lane] : 0;
        float2 adv = *(const float2*)(ad + n * NH + 2 * w);
        float e0 = -1e30f, e1 = -1e30f;
        if (lane < deg) {
            float2 av = *(const float2*)(as + (long)src * NH + 2 * w);
            e0 = leaky(av.x + adv.x);
            e1 = leaky(av.y + adv.y);
        }
        float m0 = e0, m1 = e1;
        for (int m = 32; m; m >>= 1) {
            m0 = fmaxf(m0, __shfl_xor(m0, m));
            m1 = fmaxf(m1, __shfl_xor(m1, m));
        }
        float x0 = (lane < deg) ? __expf(e0 - m0) : 0.f;
        float x1 = (lane < deg) ? __expf(e1 - m1) : 0.f;
        float s0 = x0, s1 = x1;
        for (int m = 32; m; m >>= 1) {
            s0 += __shfl_xor(s0, m);
            s1 += __shfl_xor(s1, m);
        }
        if (lane < deg) {
            sal[lane * NH + 2 * w]     = x0 / (s0 + 1e-16f);
            sal[lane * NH + 2 * w + 1] = x1 / (s1 + 1e-16f);
            if (w == 0) sidx[lane] = src;
        }
        __syncthreads();
        for (int j = 0; j < deg; j++) {
            int src2 = sidx[j];
            float a = sal[j * NH + hd];
            f16x2 v = *(const f16x2*)(h + (long)src2 * HC2 + 2 * t);
            a0 += a * (float)v[0];
            a1 += a * (float)v[1];
        }
    } else {
        float2 adv = *(const float2*)(ad + n * NH + 2 * w);
        float m0 = -1e30f, m1 = -1e30f;
        for (int j = lane; j < deg; j += 64) {
            float2 av = *(const float2*)(as + (long)colidx[k0 + j] * NH + 2 * w);
            m0 = fmaxf(m0, leaky(av.x + adv.x));
            m1 = fmaxf(m1, leaky(av.y + adv.y));
        }
        for (int m = 32; m; m >>= 1) {
            m0 = fmaxf(m0, __shfl_xor(m0, m));
            m1 = fmaxf(m1, __shfl_xor(m1, m));
        }
        float s0 = 0.f, s1 = 0.f;
        for (int j = lane; j < deg; j += 64) {
            float2 av = *(const float2*)(as + (long)colidx[k0 + j] * NH + 2 * w);
            s0 += __expf(leaky(av.x + adv.x) - m0);
            s1 += __expf(leaky(av.y + adv.y) - m1);
        }
        for (int m = 32; m; m >>= 1) {
            s0 += __shfl_xor(s0, m);
            s1 += __shfl_xor(s1, m);
        }
        float i0 = 1.f / (s0 + 1e-16f), i1 = 1.f / (s1 + 1e-16f);
        for (int c0 = 0; c0 < deg; c0 += 64) {
            int cn = min(64, deg - c0);
            __syncthreads();
            if (lane < cn) {
                int src = colidx[k0 + c0 + lane];
                float2 av = *(const float2*)(as + (long)src * NH + 2 * w);
                sal[lane * NH + 2 * w]     = __expf(leaky(av.x + adv.x) - m0) * i0;
                sal[lane * NH + 2 * w + 1] = __expf(leaky(av.y + adv.y) - m1) * i1;
                if (w == 0) sidx[lane] = src;
            }
            __syncthreads();
            for (int j = 0; j < cn; j++) {
                int src2 = sidx[j];
                float a = sal[j * NH + hd];
                f16x2 v = *(const f16x2*)(h + (long)src2 * HC2 + 2 * t);
                a0 += a * (float)v[0];
                a1 += a * (float)v[1];
            }
        }
    }
    facc[2 * t] = a0;
    facc[2 * t + 1] = a1;
    __syncthreads();
    if (t < C2) {
        float s = 0.f;
#pragma unroll
        for (int hh = 0; hh < NH; hh++) s += facc[hh * C2 + t];
        s = s * 0.1f + bias[t];
        out[(long)n * C2 + t] = s > 0.f ? s : 0.f;
    }
}

// ---------------- host ----------------
extern "C" void kernel_launch(void* const* d_in, const int* in_sizes, int n_in,
                              void* d_out, int out_size, void* d_ws, size_t ws_size,
                              hipStream_t stream) {
    const float* x      = (const float*)d_in[0];
    const int*   ei     = (const int*)d_in[1];
    const float* W1     = (const float*)d_in[2];
    const float* asrc1  = (const float*)d_in[3];
    const float* adst1  = (const float*)d_in[4];
    const float* b1     = (const float*)d_in[5];
    const float* W2     = (const float*)d_in[6];
    const float* asrc2  = (const float*)d_in[7];
    const float* adst2  = (const float*)d_in[8];
    const float* b2     = (const float*)d_in[9];
    float* out = (float*)d_out;
    const int E  = in_sizes[1] / 2;
    const int EN = E + NN;

    char* base = (char*)d_ws;
    size_t o = 0;
    auto alloc = [&](size_t bytes) { size_t r = o; o += (bytes + 255) & ~(size_t)255; return r; };
    _Float16* A1    = (_Float16*)(base + alloc((size_t)MP * K1P * 2));
    _Float16* W1t   = (_Float16*)(base + alloc((size_t)HC1 * K1P * 2));
    _Float16* A2    = (_Float16*)(base + alloc((size_t)MP * HC1 * 2));
    _Float16* W2t   = (_Float16*)(base + alloc((size_t)HC2 * HC1 * 2));
    _Float16* h1pre = (_Float16*)(base + alloc((size_t)MP * HC1 * 2));
    _Float16* h2pre = (_Float16*)(base + alloc((size_t)MP * HC2 * 2));
    float* as1      = (float*)(base + alloc((size_t)NN * NH * 4));
    float* ad1      = (float*)(base + alloc((size_t)NN * NH * 4));
    float* as2      = (float*)(base + alloc((size_t)NN * NH * 4));
    float* ad2      = (float*)(base + alloc((size_t)NN * NH * 4));
    int* counts     = (int*)(base + alloc((size_t)(NN + 1) * 4));
    int* rowptr     = (int*)(base + alloc((size_t)(NN + 1) * 4));
    int* cursor     = (int*)(base + alloc((size_t)(NN + 1) * 4));
    int* colidx     = (int*)(base + alloc((size_t)EN * 4));
    (void)ws_size; (void)n_in; (void)out_size;

    // ---- layer 1 GEMM: h1pre(fp16) = x @ W1 ----
    k_cast_pad4<<<(MP * (K1P / 4) + 255) / 256, 256, 0, stream>>>(x, A1, NN, FIN / 4, K1P / 4);
    k_transpose_W<<<dim3(K1P / 32, HC1 / 32), 256, 0, stream>>>(W1, W1t, FIN, HC1, K1P);
    k_gemm<<<8 * (MP / 256 / 8) * (HC1 / 128), 256, 0, stream>>>(A1, W1t, h1pre, K1P, HC1, HC1 / 128);

    // ---- CSR (shared by both layers) ----
    hipMemsetAsync(counts, 0, (size_t)(NN + 1) * 4, stream);
    k_csr_count<<<(E + 255) / 256, 256, 0, stream>>>(ei, counts, E);
    k_scan<<<1, 1024, 0, stream>>>(counts, rowptr, cursor, NN);
    k_csr_fill<<<(EN + 255) / 256, 256, 0, stream>>>(ei, cursor, colidx, E, NN);

    // ---- layer 1: logits + fused softmax/aggregate -> A2 (pad rows zeroed inside) ----
    k_alpha<<<NN, 256, 0, stream>>>(h1pre, asrc1, adst1, as1, ad1, C1);
    k_agg1<<<MP, 320, 0, stream>>>(rowptr, colidx, as1, ad1, h1pre, b1, A2);

    // ---- layer 2 GEMM: h2pre(fp16) = A2 @ W2 ----
    k_transpose_W<<<dim3(HC1 / 32, HC2 / 32), 256, 0, stream>>>(W2, W2t, HC1, HC2, HC1);
    k_gemm<<<8 * (MP / 256 / 8) * (HC2 / 128), 256, 0, stream>>>(A2, W2t, h2pre, HC1, HC2, HC2 / 128);

    // ---- layer 2: logits + fused softmax/aggregate + head mean ----
    k_alpha<<<NN, 256, 0, stream>>>(h2pre, asrc2, adst2, as2, ad2, C2);
    k_agg2<<<NN, 320, 0, stream>>>(rowptr, colidx, as2, ad2, h2pre, b2, out);
}

// Round 9
// 392.115 us; speedup vs baseline: 1.2417x; 1.1021x over previous
//
#include <hip/hip_runtime.h>

// ---------------- problem constants ----------------
#define NN    10000          // nodes
#define FIN   2000           // input features
#define NH    10             // heads
#define C1    128            // layer-1 out channels per head
#define C2    64             // layer-2 out channels per head
#define HC1   1280           // NH*C1
#define HC2   640            // NH*C2
#define MP    10240          // nodes padded to 256*40 (BM=256 tiles, XCD swizzle needs 40 m-tiles)
#define K1P   2016           // FIN padded to 32 multiple (63*32)

typedef _Float16 f16x8 __attribute__((ext_vector_type(8)));
typedef _Float16 f16x4 __attribute__((ext_vector_type(4)));
typedef _Float16 f16x2 __attribute__((ext_vector_type(2)));
typedef float    f32x4 __attribute__((ext_vector_type(4)));

__device__ __forceinline__ float leaky(float x) { return x > 0.f ? x : 0.2f * x; }

// ---------------- fp32 -> fp16 cast + pad, float4-vectorized, 2D grid (no int div) ----------------
__global__ void k_cast_pad4(const float* __restrict__ src, _Float16* __restrict__ dst,
                            int R, int C4, int Cp4) {
    int c = blockIdx.x * 256 + threadIdx.x;
    int r = blockIdx.y;
    if (c >= Cp4) return;
    float4 v = make_float4(0.f, 0.f, 0.f, 0.f);
    if (r < R && c < C4) v = *(const float4*)(src + (long)r * (C4 * 4) + 4 * c);
    f16x4 o = {(_Float16)v.x, (_Float16)v.y, (_Float16)v.z, (_Float16)v.w};
    *(f16x4*)(dst + (long)r * (Cp4 * 4) + 4 * c) = o;
}

// ---------------- W [K][N] -> Wt fp16 [N][Kpad] (zero k-pad) ----------------
__global__ void k_transpose_W(const float* __restrict__ W, _Float16* __restrict__ Wt,
                              int K, int N, int Kpad) {
    __shared__ float tile[32][33];
    int tx = threadIdx.x & 31;
    int ty = threadIdx.x >> 5;           // 0..7
    int kbase = blockIdx.x * 32;
    int nbase = blockIdx.y * 32;
#pragma unroll
    for (int i = 0; i < 4; i++) {
        int k = kbase + ty + i * 8;
        float v = (k < K) ? W[(long)k * N + nbase + tx] : 0.0f;
        tile[ty + i * 8][tx] = v;
    }
    __syncthreads();
#pragma unroll
    for (int i = 0; i < 4; i++) {
        int n = nbase + ty + i * 8;
        Wt[(long)n * Kpad + kbase + tx] = (_Float16)tile[tx][ty + i * 8];
    }
}

// ---------------- async global->LDS helper ----------------
__device__ __forceinline__ void gl2lds16(const void* g, void* l) {
    __builtin_amdgcn_global_load_lds((const __attribute__((address_space(1))) void*)g,
                                     (__attribute__((address_space(3))) void*)l, 16, 0, 0);
}

// s_waitcnt immediates (gfx9 encoding: vmcnt[3:0] | expcnt<<4 | lgkmcnt<<8 | vmcnt[5:4]<<14)
#define WAITCNT_VM6  0x0F76   // vmcnt<=6 (one 6-load stage may remain in flight)
#define WAITCNT_VM0  0x0F70   // vmcnt==0

// ---------------- fp16 MFMA GEMM + fused attention logits ----------------
// C[MpxN](fp16) = A[MpxK] * Bt[NxK]^T. BM=256 x BN=128, 4 waves (2x2), wave
// tile 128x64. Tri-buffered LDS, raw s_barrier + s_waitcnt vmcnt(6).
// Epilogue ALSO computes as/ad logits (dot of each h-row with asf/adf) from
// the fp32 acc: q-lane shuffle butterfly + LDS cross-wave combine.
// headw = per-head col width (128 -> 1 head/block spans both wc; 64 -> wc=head).
__global__ __launch_bounds__(256, 2) void k_gemm(const _Float16* __restrict__ A,
                                                 const _Float16* __restrict__ Bt,
                                                 _Float16* __restrict__ C, int K, int N,
                                                 int NTN,
                                                 const float* __restrict__ asf,
                                                 const float* __restrict__ adf,
                                                 float* __restrict__ as,
                                                 float* __restrict__ ad,
                                                 int headw) {
    __shared__ char smem[73728] __attribute__((aligned(16)));
    _Float16* As = (_Float16*)smem;             // 3 x 8192 fp16 (16KB each)
    _Float16* Bs = (_Float16*)(smem + 49152);   // 3 x 4096 fp16 (8KB each)

    int bid = blockIdx.x;
    int r = bid & 7, qb = bid >> 3;
    int n_t = qb % NTN;
    int m_t = r + 8 * (qb / NTN);
    int m0 = m_t * 256;
    int n0 = n_t * 128;
    int t = threadIdx.x;
    int lane = t & 63, wave = t >> 6;
    int wr = wave >> 1, wc = wave & 1;
    int lrow = lane & 15, q = lane >> 4;

    f32x4 acc[8][4] = {};

    int sA[4], sB[2];
#pragma unroll
    for (int i = 0; i < 4; i++) sA[i] = t + 256 * i;
#pragma unroll
    for (int i = 0; i < 2; i++) sB[i] = t + 256 * i;
    const _Float16* Ar[4];
    const _Float16* Br[2];
#pragma unroll
    for (int i = 0; i < 4; i++) {
        int row = sA[i] >> 2, gq = (sA[i] & 3) ^ ((sA[i] >> 3) & 3);
        Ar[i] = A + (long)(m0 + row) * K + gq * 8;
    }
#pragma unroll
    for (int i = 0; i < 2; i++) {
        int row = sB[i] >> 2, gq = (sB[i] & 3) ^ ((sB[i] >> 3) & 3);
        Br[i] = Bt + (long)(n0 + row) * K + gq * 8;
    }

    int aoff[8], boff[4];
#pragma unroll
    for (int i = 0; i < 8; i++) {
        int rowa = wr * 128 + i * 16 + lrow;
        aoff[i] = rowa * 32 + ((q ^ ((rowa >> 1) & 3)) << 3);
    }
#pragma unroll
    for (int i = 0; i < 4; i++) {
        int rowb = wc * 64 + i * 16 + lrow;
        boff[i] = rowb * 32 + ((q ^ ((rowb >> 1) & 3)) << 3);
    }

    auto stage = [&](int it, int buf) {
        int k0 = it << 5;
#pragma unroll
        for (int i = 0; i < 4; i++) gl2lds16(Ar[i] + k0, &As[buf * 8192 + sA[i] * 8]);
#pragma unroll
        for (int i = 0; i < 2; i++) gl2lds16(Br[i] + k0, &Bs[buf * 4096 + sB[i] * 8]);
    };

    int nk = K >> 5;
    stage(0, 0);
    stage(1, 1);
    int cur = 0;
    for (int it = 0; it < nk; it++) {
        if (it + 1 < nk) __builtin_amdgcn_s_waitcnt(WAITCNT_VM6);
        else             __builtin_amdgcn_s_waitcnt(WAITCNT_VM0);
        __builtin_amdgcn_s_barrier();
        int nxt = cur + 2; if (nxt >= 3) nxt -= 3;
        if (it + 2 < nk) stage(it + 2, nxt);

        f16x8 af[8], bf[4];
#pragma unroll
        for (int i = 0; i < 8; i++) af[i] = *(const f16x8*)&As[cur * 8192 + aoff[i]];
#pragma unroll
        for (int i = 0; i < 4; i++) bf[i] = *(const f16x8*)&Bs[cur * 4096 + boff[i]];
#pragma unroll
        for (int mt = 0; mt < 8; mt++)
#pragma unroll
            for (int nt = 0; nt < 4; nt++)
                acc[mt][nt] = __builtin_amdgcn_mfma_f32_16x16x32_f16(bf[nt], af[mt], acc[mt][nt], 0, 0, 0);
        cur = (cur + 1 == 3) ? 0 : cur + 1;
    }

    // ---- C store: lane holds C[m][n..n+3] per fragment -> packed 8B stores ----
#pragma unroll
    for (int mt = 0; mt < 8; mt++) {
        int m = m0 + wr * 128 + mt * 16 + lrow;
#pragma unroll
        for (int nt = 0; nt < 4; nt++) {
            int n = n0 + wc * 64 + nt * 16 + q * 4;
            f16x4 o = {(_Float16)acc[mt][nt][0], (_Float16)acc[mt][nt][1],
                       (_Float16)acc[mt][nt][2], (_Float16)acc[mt][nt][3]};
            *(f16x4*)(C + (long)m * N + n) = o;
        }
    }

    // ---- fused logits: as/ad = h-row . asf/adf per head ----
    float4 av[4], dvv[4];
#pragma unroll
    for (int nt = 0; nt < 4; nt++) {
        av[nt]  = *(const float4*)(asf + n0 + wc * 64 + nt * 16 + q * 4);
        dvv[nt] = *(const float4*)(adf + n0 + wc * 64 + nt * 16 + q * 4);
    }
    __syncthreads();                       // done reading As/Bs; reuse smem
    float* sAs = (float*)smem;             // 512 floats
    float* sAd = (float*)smem + 512;       // 512 floats
#pragma unroll
    for (int mt = 0; mt < 8; mt++) {
        float ps = 0.f, pd = 0.f;
#pragma unroll
        for (int nt = 0; nt < 4; nt++) {
            ps += acc[mt][nt][0] * av[nt].x + acc[mt][nt][1] * av[nt].y
                + acc[mt][nt][2] * av[nt].z + acc[mt][nt][3] * av[nt].w;
            pd += acc[mt][nt][0] * dvv[nt].x + acc[mt][nt][1] * dvv[nt].y
                + acc[mt][nt][2] * dvv[nt].z + acc[mt][nt][3] * dvv[nt].w;
        }
        ps += __shfl_xor(ps, 16); ps += __shfl_xor(ps, 32);   // reduce over q lanes
        pd += __shfl_xor(pd, 16); pd += __shfl_xor(pd, 32);
        if (q == 0) {
            int rl = wr * 128 + mt * 16 + lrow;
            sAs[rl * 2 + wc] = ps;
            sAd[rl * 2 + wc] = pd;
        }
    }
    __syncthreads();
    {
        int m = m0 + t;
        if (m < NN) {
            int hb = n0 / headw;
            if (headw == 128) {            // 1 head spans both wc halves
                as[m * NH + hb] = sAs[t * 2] + sAs[t * 2 + 1];
                ad[m * NH + hb] = sAd[t * 2] + sAd[t * 2 + 1];
            } else {                       // wc half = head
                as[m * NH + hb]     = sAs[t * 2];
                as[m * NH + hb + 1] = sAs[t * 2 + 1];
                ad[m * NH + hb]     = sAd[t * 2];
                ad[m * NH + hb + 1] = sAd[t * 2 + 1];
            }
        }
    }
}

// ---------------- CSR build ----------------
__global__ void k_csr_count(const int* __restrict__ ei, int* counts, int E) {
    int e = blockIdx.x * 256 + threadIdx.x;
    if (e < E) atomicAdd(&counts[ei[E + e]], 1);
}
// single-pass chunked exclusive scan of (counts[i] + 1); the +1 is the self-loop
__global__ void k_scan(const int* __restrict__ counts, int* rowptr, int* cursor, int n) {
    __shared__ int s[1024];
    int t = threadIdx.x;
    const int CH = (NN + 1023) / 1024;     // 10
    int base = t * CH;
    int loc[CH];
    int sum = 0;
#pragma unroll
    for (int i = 0; i < CH; i++) {
        int idx = base + i;
        int v = (idx < n) ? (counts[idx] + 1) : 0;
        loc[i] = sum;
        sum += v;
    }
    s[t] = sum;
    __syncthreads();
    for (int off = 1; off < 1024; off <<= 1) {
        int add = (t >= off) ? s[t - off] : 0;
        __syncthreads();
        s[t] += add;
        __syncthreads();
    }
    int pre = (t > 0) ? s[t - 1] : 0;
#pragma unroll
    for (int i = 0; i < CH; i++) {
        int idx = base + i;
        if (idx < n) { int ex = pre + loc[i]; rowptr[idx] = ex; cursor[idx] = ex; }
    }
    if (t == 1023) rowptr[n] = s[1023];
}
__global__ void k_csr_fill(const int* __restrict__ ei, int* cursor, int* colidx, int E, int n) {
    int i = blockIdx.x * 256 + threadIdx.x;
    if (i >= E + n) return;
    int s, d;
    if (i < E) { s = ei[i]; d = ei[E + i]; }
    else       { s = i - E; d = i - E; }
    int pos = atomicAdd(&cursor[d], 1);
    colidx[pos] = s;
}

// ---------------- layer-1: FUSED softmax + wide-row aggregation -> A2 fp16 ----------------
// 320 threads. Softmax phase: wave w (0..4) computes alpha for heads 2w,2w+1
// (logits read as one float2 per src) into LDS. Gather phase: thread t owns
// channels 4t..4t+3 (head = t>>5), f16x4 row gather.
// grid = MP: pad rows (n >= NN) write zeros.
__global__ __launch_bounds__(320) void k_agg1(const int* __restrict__ rowptr,
                                              const int* __restrict__ colidx,
                                              const float* __restrict__ as,
                                              const float* __restrict__ ad,
                                              const _Float16* __restrict__ h,
                                              const float* __restrict__ bias,
                                              _Float16* __restrict__ A2) {
    __shared__ int sidx[64];
    __shared__ float sal[64 * NH];
    int n = blockIdx.x, t = threadIdx.x;
    if (n >= NN) {
        f16x4 z = {(_Float16)0.f, (_Float16)0.f, (_Float16)0.f, (_Float16)0.f};
        *(f16x4*)(A2 + (long)n * HC1 + 4 * t) = z;
        return;
    }
    int k0 = rowptr[n], deg = rowptr[n + 1] - k0;
    int w = t >> 6, lane = t & 63;
    int hd = t >> 5;
    float acc[4] = {0, 0, 0, 0};

    if (deg <= 64) {
        int src = (lane < deg) ? colidx[k0 + lane] : 0;
        float2 adv = *(const float2*)(ad + n * NH + 2 * w);
        float e0 = -1e30f, e1 = -1e30f;
        if (lane < deg) {
            float2 avv = *(const float2*)(as + (long)src * NH + 2 * w);
            e0 = leaky(avv.x + adv.x);
            e1 = leaky(avv.y + adv.y);
        }
        float m0 = e0, m1 = e1;
        for (int m = 32; m; m >>= 1) {
            m0 = fmaxf(m0, __shfl_xor(m0, m));
            m1 = fmaxf(m1, __shfl_xor(m1, m));
        }
        float x0 = (lane < deg) ? __expf(e0 - m0) : 0.f;
        float x1 = (lane < deg) ? __expf(e1 - m1) : 0.f;
        float s0 = x0, s1 = x1;
        for (int m = 32; m; m >>= 1) {
            s0 += __shfl_xor(s0, m);
            s1 += __shfl_xor(s1, m);
        }
        if (lane < deg) {
            sal[lane * NH + 2 * w]     = x0 / (s0 + 1e-16f);
            sal[lane * NH + 2 * w + 1] = x1 / (s1 + 1e-16f);
            if (w == 0) sidx[lane] = src;
        }
        __syncthreads();
        for (int j = 0; j < deg; j++) {
            int src2 = sidx[j];
            float a = sal[j * NH + hd];
            f16x4 v = *(const f16x4*)(h + (long)src2 * HC1 + 4 * t);
            acc[0] += a * (float)v[0];
            acc[1] += a * (float)v[1];
            acc[2] += a * (float)v[2];
            acc[3] += a * (float)v[3];
        }
    } else {
        float2 adv = *(const float2*)(ad + n * NH + 2 * w);
        float m0 = -1e30f, m1 = -1e30f;
        for (int j = lane; j < deg; j += 64) {
            float2 avv = *(const float2*)(as + (long)colidx[k0 + j] * NH + 2 * w);
            m0 = fmaxf(m0, leaky(avv.x + adv.x));
            m1 = fmaxf(m1, leaky(avv.y + adv.y));
        }
        for (int m = 32; m; m >>= 1) {
            m0 = fmaxf(m0, __shfl_xor(m0, m));
            m1 = fmaxf(m1, __shfl_xor(m1, m));
        }
        float s0 = 0.f, s1 = 0.f;
        for (int j = lane; j < deg; j += 64) {
            float2 avv = *(const float2*)(as + (long)colidx[k0 + j] * NH + 2 * w);
            s0 += __expf(leaky(avv.x + adv.x) - m0);
            s1 += __expf(leaky(avv.y + adv.y) - m1);
        }
        for (int m = 32; m; m >>= 1) {
            s0 += __shfl_xor(s0, m);
            s1 += __shfl_xor(s1, m);
        }
        float i0 = 1.f / (s0 + 1e-16f), i1 = 1.f / (s1 + 1e-16f);
        for (int c0 = 0; c0 < deg; c0 += 64) {
            int cn = min(64, deg - c0);
            __syncthreads();
            if (lane < cn) {
                int src = colidx[k0 + c0 + lane];
                float2 avv = *(const float2*)(as + (long)src * NH + 2 * w);
                sal[lane * NH + 2 * w]     = __expf(leaky(avv.x + adv.x) - m0) * i0;
                sal[lane * NH + 2 * w + 1] = __expf(leaky(avv.y + adv.y) - m1) * i1;
                if (w == 0) sidx[lane] = src;
            }
            __syncthreads();
            for (int j = 0; j < cn; j++) {
                int src2 = sidx[j];
                float a = sal[j * NH + hd];
                f16x4 v = *(const f16x4*)(h + (long)src2 * HC1 + 4 * t);
                acc[0] += a * (float)v[0];
                acc[1] += a * (float)v[1];
                acc[2] += a * (float)v[2];
                acc[3] += a * (float)v[3];
            }
        }
    }
    f16x4 o;
#pragma unroll
    for (int i = 0; i < 4; i++) {
        float x = acc[i] + bias[4 * t + i];
        o[i] = (_Float16)(x > 0.f ? x : 0.f);
    }
    *(f16x4*)(A2 + (long)n * HC1 + 4 * t) = o;
}

// ---------------- layer-2: FUSED softmax + aggregation + head mean + bias + relu ----------------
__global__ __launch_bounds__(320) void k_agg2(const int* __restrict__ rowptr,
                                              const int* __restrict__ colidx,
                                              const float* __restrict__ as,
                                              const float* __restrict__ ad,
                                              const _Float16* __restrict__ h,
                                              const float* __restrict__ bias,
                                              float* __restrict__ out) {
    __shared__ int sidx[64];
    __shared__ float sal[64 * NH];
    __shared__ float facc[HC2];
    int n = blockIdx.x, t = threadIdx.x;
    int k0 = rowptr[n], deg = rowptr[n + 1] - k0;
    int w = t >> 6, lane = t & 63;
    int hd = t >> 5;
    float a0 = 0.f, a1 = 0.f;

    if (deg <= 64) {
        int src = (lane < deg) ? colidx[k0 + lane] : 0;
        float2 adv = *(const float2*)(ad + n * NH + 2 * w);
        float e0 = -1e30f, e1 = -1e30f;
        if (lane < deg) {
            float2 avv = *(const float2*)(as + (long)src * NH + 2 * w);
            e0 = leaky(avv.x + adv.x);
            e1 = leaky(avv.y + adv.y);
        }
        float m0 = e0, m1 = e1;
        for (int m = 32; m; m >>= 1) {
            m0 = fmaxf(m0, __shfl_xor(m0, m));
            m1 = fmaxf(m1, __shfl_xor(m1, m));
        }
        float x0 = (lane < deg) ? __expf(e0 - m0) : 0.f;
        float x1 = (lane < deg) ? __expf(e1 - m1) : 0.f;
        float s0 = x0, s1 = x1;
        for (int m = 32; m; m >>= 1) {
            s0 += __shfl_xor(s0, m);
            s1 += __shfl_xor(s1, m);
        }
        if (lane < deg) {
            sal[lane * NH + 2 * w]     = x0 / (s0 + 1e-16f);
            sal[lane * NH + 2 * w + 1] = x1 / (s1 + 1e-16f);
            if (w == 0) sidx[lane] = src;
        }
        __syncthreads();
        for (int j = 0; j < deg; j++) {
            int src2 = sidx[j];
            float a = sal[j * NH + hd];
            f16x2 v = *(const f16x2*)(h + (long)src2 * HC2 + 2 * t);
            a0 += a * (float)v[0];
            a1 += a * (float)v[1];
        }
    } else {
        float2 adv = *(const float2*)(ad + n * NH + 2 * w);
        float m0 = -1e30f, m1 = -1e30f;
        for (int j = lane; j < deg; j += 64) {
            float2 avv = *(const float2*)(as + (long)colidx[k0 + j] * NH + 2 * w);
            m0 = fmaxf(m0, leaky(avv.x + adv.x));
            m1 = fmaxf(m1, leaky(avv.y + adv.y));
        }
        for (int m = 32; m; m >>= 1) {
            m0 = fmaxf(m0, __shfl_xor(m0, m));
            m1 = fmaxf(m1, __shfl_xor(m1, m));
        }
        float s0 = 0.f, s1 = 0.f;
        for (int j = lane; j < deg; j += 64) {
            float2 avv = *(const float2*)(as + (long)colidx[k0 + j] * NH + 2 * w);
            s0 += __expf(leaky(avv.x + adv.x) - m0);
            s1 += __expf(leaky(avv.y + adv.y) - m1);
        }
        for (int m = 32; m; m >>= 1) {
            s0 += __shfl_xor(s0, m);
            s1 += __shfl_xor(s1, m);
        }
        float i0 = 1.f / (s0 + 1e-16f), i1 = 1.f / (s1 + 1e-16f);
        for (int c0 = 0; c0 < deg; c0 += 64) {
            int cn = min(64, deg - c0);
            __syncthreads();
            if (lane < cn) {
                int src = colidx[k0 + c0 + lane];
                float2 avv = *(const float2*)(as + (long)src * NH + 2 * w);
                sal[lane * NH + 2 * w]     = __expf(leaky(avv.x + adv.x) - m0) * i0;
                sal[lane * NH + 2 * w + 1] = __expf(leaky(avv.y + adv.y) - m1) * i1;
                if (w == 0) sidx[lane] = src;
            }
            __syncthreads();
            for (int j = 0; j < cn; j++) {
                int src2 = sidx[j];
                float a = sal[j * NH + hd];
                f16x2 v = *(const f16x2*)(h + (long)src2 * HC2 + 2 * t);
                a0 += a * (float)v[0];
                a1 += a * (float)v[1];
            }
        }
    }
    facc[2 * t] = a0;
    facc[2 * t + 1] = a1;
    __syncthreads();
    if (t < C2) {
        float s = 0.f;
#pragma unroll
        for (int hh = 0; hh < NH; hh++) s += facc[hh * C2 + t];
        s = s * 0.1f + bias[t];
        out[(long)n * C2 + t] = s > 0.f ? s : 0.f;
    }
}

// ---------------- host ----------------
extern "C" void kernel_launch(void* const* d_in, const int* in_sizes, int n_in,
                              void* d_out, int out_size, void* d_ws, size_t ws_size,
                              hipStream_t stream) {
    const float* x      = (const float*)d_in[0];
    const int*   ei     = (const int*)d_in[1];
    const float* W1     = (const float*)d_in[2];
    const float* asrc1  = (const float*)d_in[3];
    const float* adst1  = (const float*)d_in[4];
    const float* b1     = (const float*)d_in[5];
    const float* W2     = (const float*)d_in[6];
    const float* asrc2  = (const float*)d_in[7];
    const float* adst2  = (const float*)d_in[8];
    const float* b2     = (const float*)d_in[9];
    float* out = (float*)d_out;
    const int E  = in_sizes[1] / 2;
    const int EN = E + NN;

    char* base = (char*)d_ws;
    size_t o = 0;
    auto alloc = [&](size_t bytes) { size_t r = o; o += (bytes + 255) & ~(size_t)255; return r; };
    _Float16* A1    = (_Float16*)(base + alloc((size_t)MP * K1P * 2));
    _Float16* W1t   = (_Float16*)(base + alloc((size_t)HC1 * K1P * 2));
    _Float16* A2    = (_Float16*)(base + alloc((size_t)MP * HC1 * 2));
    _Float16* W2t   = (_Float16*)(base + alloc((size_t)HC2 * HC1 * 2));
    _Float16* h1pre = (_Float16*)(base + alloc((size_t)MP * HC1 * 2));
    _Float16* h2pre = (_Float16*)(base + alloc((size_t)MP * HC2 * 2));
    float* as1      = (float*)(base + alloc((size_t)NN * NH * 4));
    float* ad1      = (float*)(base + alloc((size_t)NN * NH * 4));
    float* as2      = (float*)(base + alloc((size_t)NN * NH * 4));
    float* ad2      = (float*)(base + alloc((size_t)NN * NH * 4));
    int* counts     = (int*)(base + alloc((size_t)(NN + 1) * 4));
    int* rowptr     = (int*)(base + alloc((size_t)(NN + 1) * 4));
    int* cursor     = (int*)(base + alloc((size_t)(NN + 1) * 4));
    int* colidx     = (int*)(base + alloc((size_t)EN * 4));
    (void)ws_size; (void)n_in; (void)out_size;

    // ---- layer 1 GEMM (+ fused logits): h1pre(fp16), as1/ad1 ----
    k_cast_pad4<<<dim3((K1P / 4 + 255) / 256, MP), 256, 0, stream>>>(x, A1, NN, FIN / 4, K1P / 4);
    k_transpose_W<<<dim3(K1P / 32, HC1 / 32), 256, 0, stream>>>(W1, W1t, FIN, HC1, K1P);
    k_gemm<<<8 * (MP / 256 / 8) * (HC1 / 128), 256, 0, stream>>>(A1, W1t, h1pre, K1P, HC1, HC1 / 128,
                                                                 asrc1, adst1, as1, ad1, C1);

    // ---- CSR (shared by both layers) ----
    hipMemsetAsync(counts, 0, (size_t)(NN + 1) * 4, stream);
    k_csr_count<<<(E + 255) / 256, 256, 0, stream>>>(ei, counts, E);
    k_scan<<<1, 1024, 0, stream>>>(counts, rowptr, cursor, NN);
    k_csr_fill<<<(EN + 255) / 256, 256, 0, stream>>>(ei, cursor, colidx, E, NN);

    // ---- layer 1: fused softmax/aggregate -> A2 (pad rows zeroed inside) ----
    k_agg1<<<MP, 320, 0, stream>>>(rowptr, colidx, as1, ad1, h1pre, b1, A2);

    // ---- layer 2 GEMM (+ fused logits): h2pre(fp16), as2/ad2 ----
    k_transpose_W<<<dim3(HC1 / 32, HC2 / 32), 256, 0, stream>>>(W2, W2t, HC1, HC2, HC1);
    k_gemm<<<8 * (MP / 256 / 8) * (HC2 / 128), 256, 0, stream>>>(A2, W2t, h2pre, HC1, HC2, HC2 / 128,
                                                                 asrc2, adst2, as2, ad2, C2);

    // ---- layer 2: fused softmax/aggregate + head mean ----
    k_agg2<<<NN, 320, 0, stream>>>(rowptr, colidx, as2, ad2, h2pre, b2, out);
}

// Round 10
// 379.322 us; speedup vs baseline: 1.2836x; 1.0337x over previous
//
#include <hip/hip_runtime.h>

// ---------------- problem constants ----------------
#define NN    10000          // nodes
#define FIN   2000           // input features
#define NH    10             // heads
#define C1    128            // layer-1 out channels per head
#define C2    64             // layer-2 out channels per head
#define HC1   1280           // NH*C1
#define HC2   640            // NH*C2
#define MP    10240          // nodes padded to 256*40 (BM=256 tiles, XCD swizzle needs 40 m-tiles)
#define K1P   2016           // FIN padded to 32 multiple (63*32)

typedef _Float16 f16x8 __attribute__((ext_vector_type(8)));
typedef _Float16 f16x4 __attribute__((ext_vector_type(4)));
typedef _Float16 f16x2 __attribute__((ext_vector_type(2)));
typedef float    f32x4 __attribute__((ext_vector_type(4)));

__device__ __forceinline__ float leaky(float x) { return x > 0.f ? x : 0.2f * x; }

// ---------------- fp32 -> fp16 cast + pad, float4-vectorized + CSR edge count side-job ----------------
// grid (2, MP). Side-job: x==1 blocks with y*256+t < E do the dst-degree atomic count
// (counts zeroed by k_transpose_both, which runs before this on the stream).
__global__ void k_cast_count(const float* __restrict__ src, _Float16* __restrict__ dst,
                             int R, int C4, int Cp4,
                             const int* __restrict__ ei, int* __restrict__ counts, int E) {
    if (blockIdx.x == 1) {
        int e = blockIdx.y * 256 + threadIdx.x;
        if (e < E) atomicAdd(&counts[ei[E + e]], 1);
    }
    int c = blockIdx.x * 256 + threadIdx.x;
    int r = blockIdx.y;
    if (c >= Cp4) return;
    float4 v = make_float4(0.f, 0.f, 0.f, 0.f);
    if (r < R && c < C4) v = *(const float4*)(src + (long)r * (C4 * 4) + 4 * c);
    f16x4 o = {(_Float16)v.x, (_Float16)v.y, (_Float16)v.z, (_Float16)v.w};
    *(f16x4*)(dst + (long)r * (Cp4 * 4) + 4 * c) = o;
}

// ---------------- both W transposes in one launch + zero counts ----------------
// grid (63, 60): y<40 -> W1 [FIN][HC1] -> W1t [HC1][K1P]; y>=40 -> W2 [HC1][HC2] -> W2t [HC2][HC1].
// Side-job: x==0 blocks zero counts[0..NN].
__global__ void k_transpose_both(const float* __restrict__ W1, _Float16* __restrict__ W1t,
                                 const float* __restrict__ W2, _Float16* __restrict__ W2t,
                                 int* __restrict__ counts) {
    __shared__ float tile[32][33];
    if (blockIdx.x == 0) {
        int i = blockIdx.y * 256 + threadIdx.x;
        if (i <= NN) counts[i] = 0;
    }
    const float* W; _Float16* Wt; int K, N, Kpad, kbase, nbase;
    if (blockIdx.y < 40) {
        W = W1; Wt = W1t; K = FIN; N = HC1; Kpad = K1P;
        kbase = blockIdx.x * 32; nbase = blockIdx.y * 32;
    } else {
        if (blockIdx.x >= 40) return;
        W = W2; Wt = W2t; K = HC1; N = HC2; Kpad = HC1;
        kbase = blockIdx.x * 32; nbase = (blockIdx.y - 40) * 32;
        if (nbase >= N) return;
    }
    int tx = threadIdx.x & 31;
    int ty = threadIdx.x >> 5;           // 0..7
#pragma unroll
    for (int i = 0; i < 4; i++) {
        int k = kbase + ty + i * 8;
        float v = (k < K) ? W[(long)k * N + nbase + tx] : 0.0f;
        tile[ty + i * 8][tx] = v;
    }
    __syncthreads();
#pragma unroll
    for (int i = 0; i < 4; i++) {
        int n = nbase + ty + i * 8;
        Wt[(long)n * Kpad + kbase + tx] = (_Float16)tile[tx][ty + i * 8];
    }
}

// ---------------- async global->LDS helper ----------------
__device__ __forceinline__ void gl2lds16(const void* g, void* l) {
    __builtin_amdgcn_global_load_lds((const __attribute__((address_space(1))) void*)g,
                                     (__attribute__((address_space(3))) void*)l, 16, 0, 0);
}

// s_waitcnt immediates (gfx9 encoding: vmcnt[3:0] | expcnt<<4 | lgkmcnt<<8 | vmcnt[5:4]<<14)
#define WAITCNT_VM6  0x0F76   // vmcnt<=6 (one 6-load stage may remain in flight)
#define WAITCNT_VM0  0x0F70   // vmcnt==0

// ---------------- fp16 MFMA GEMM + fused attention logits ----------------
// C[MpxN](fp16) = A[MpxK] * Bt[NxK]^T. BM=256 x BN=128, 4 waves (2x2), wave
// tile 128x64. Tri-buffered LDS, raw s_barrier + s_waitcnt vmcnt(6).
// Epilogue also computes as/ad logits from the fp32 acc.
__global__ __launch_bounds__(256, 2) void k_gemm(const _Float16* __restrict__ A,
                                                 const _Float16* __restrict__ Bt,
                                                 _Float16* __restrict__ C, int K, int N,
                                                 int NTN,
                                                 const float* __restrict__ asf,
                                                 const float* __restrict__ adf,
                                                 float* __restrict__ as,
                                                 float* __restrict__ ad,
                                                 int headw) {
    __shared__ char smem[73728] __attribute__((aligned(16)));
    _Float16* As = (_Float16*)smem;             // 3 x 8192 fp16 (16KB each)
    _Float16* Bs = (_Float16*)(smem + 49152);   // 3 x 4096 fp16 (8KB each)

    int bid = blockIdx.x;
    int r = bid & 7, qb = bid >> 3;
    int n_t = qb % NTN;
    int m_t = r + 8 * (qb / NTN);
    int m0 = m_t * 256;
    int n0 = n_t * 128;
    int t = threadIdx.x;
    int lane = t & 63, wave = t >> 6;
    int wr = wave >> 1, wc = wave & 1;
    int lrow = lane & 15, q = lane >> 4;

    f32x4 acc[8][4] = {};

    int sA[4], sB[2];
#pragma unroll
    for (int i = 0; i < 4; i++) sA[i] = t + 256 * i;
#pragma unroll
    for (int i = 0; i < 2; i++) sB[i] = t + 256 * i;
    const _Float16* Ar[4];
    const _Float16* Br[2];
#pragma unroll
    for (int i = 0; i < 4; i++) {
        int row = sA[i] >> 2, gq = (sA[i] & 3) ^ ((sA[i] >> 3) & 3);
        Ar[i] = A + (long)(m0 + row) * K + gq * 8;
    }
#pragma unroll
    for (int i = 0; i < 2; i++) {
        int row = sB[i] >> 2, gq = (sB[i] & 3) ^ ((sB[i] >> 3) & 3);
        Br[i] = Bt + (long)(n0 + row) * K + gq * 8;
    }

    int aoff[8], boff[4];
#pragma unroll
    for (int i = 0; i < 8; i++) {
        int rowa = wr * 128 + i * 16 + lrow;
        aoff[i] = rowa * 32 + ((q ^ ((rowa >> 1) & 3)) << 3);
    }
#pragma unroll
    for (int i = 0; i < 4; i++) {
        int rowb = wc * 64 + i * 16 + lrow;
        boff[i] = rowb * 32 + ((q ^ ((rowb >> 1) & 3)) << 3);
    }

    auto stage = [&](int it, int buf) {
        int k0 = it << 5;
#pragma unroll
        for (int i = 0; i < 4; i++) gl2lds16(Ar[i] + k0, &As[buf * 8192 + sA[i] * 8]);
#pragma unroll
        for (int i = 0; i < 2; i++) gl2lds16(Br[i] + k0, &Bs[buf * 4096 + sB[i] * 8]);
    };

    int nk = K >> 5;
    stage(0, 0);
    stage(1, 1);
    int cur = 0;
    for (int it = 0; it < nk; it++) {
        if (it + 1 < nk) __builtin_amdgcn_s_waitcnt(WAITCNT_VM6);
        else             __builtin_amdgcn_s_waitcnt(WAITCNT_VM0);
        __builtin_amdgcn_s_barrier();
        int nxt = cur + 2; if (nxt >= 3) nxt -= 3;
        if (it + 2 < nk) stage(it + 2, nxt);

        f16x8 af[8], bf[4];
#pragma unroll
        for (int i = 0; i < 8; i++) af[i] = *(const f16x8*)&As[cur * 8192 + aoff[i]];
#pragma unroll
        for (int i = 0; i < 4; i++) bf[i] = *(const f16x8*)&Bs[cur * 4096 + boff[i]];
#pragma unroll
        for (int mt = 0; mt < 8; mt++)
#pragma unroll
            for (int nt = 0; nt < 4; nt++)
                acc[mt][nt] = __builtin_amdgcn_mfma_f32_16x16x32_f16(bf[nt], af[mt], acc[mt][nt], 0, 0, 0);
        cur = (cur + 1 == 3) ? 0 : cur + 1;
    }

    // ---- C store: lane holds C[m][n..n+3] per fragment -> packed 8B stores ----
#pragma unroll
    for (int mt = 0; mt < 8; mt++) {
        int m = m0 + wr * 128 + mt * 16 + lrow;
#pragma unroll
        for (int nt = 0; nt < 4; nt++) {
            int n = n0 + wc * 64 + nt * 16 + q * 4;
            f16x4 o = {(_Float16)acc[mt][nt][0], (_Float16)acc[mt][nt][1],
                       (_Float16)acc[mt][nt][2], (_Float16)acc[mt][nt][3]};
            *(f16x4*)(C + (long)m * N + n) = o;
        }
    }

    // ---- fused logits: as/ad = h-row . asf/adf per head ----
    float4 av[4], dvv[4];
#pragma unroll
    for (int nt = 0; nt < 4; nt++) {
        av[nt]  = *(const float4*)(asf + n0 + wc * 64 + nt * 16 + q * 4);
        dvv[nt] = *(const float4*)(adf + n0 + wc * 64 + nt * 16 + q * 4);
    }
    __syncthreads();                       // done reading As/Bs; reuse smem
    float* sAs = (float*)smem;             // 512 floats
    float* sAd = (float*)smem + 512;       // 512 floats
#pragma unroll
    for (int mt = 0; mt < 8; mt++) {
        float ps = 0.f, pd = 0.f;
#pragma unroll
        for (int nt = 0; nt < 4; nt++) {
            ps += acc[mt][nt][0] * av[nt].x + acc[mt][nt][1] * av[nt].y
                + acc[mt][nt][2] * av[nt].z + acc[mt][nt][3] * av[nt].w;
            pd += acc[mt][nt][0] * dvv[nt].x + acc[mt][nt][1] * dvv[nt].y
                + acc[mt][nt][2] * dvv[nt].z + acc[mt][nt][3] * dvv[nt].w;
        }
        ps += __shfl_xor(ps, 16); ps += __shfl_xor(ps, 32);   // reduce over q lanes
        pd += __shfl_xor(pd, 16); pd += __shfl_xor(pd, 32);
        if (q == 0) {
            int rl = wr * 128 + mt * 16 + lrow;
            sAs[rl * 2 + wc] = ps;
            sAd[rl * 2 + wc] = pd;
        }
    }
    __syncthreads();
    {
        int m = m0 + t;
        if (m < NN) {
            int hb = n0 / headw;
            if (headw == 128) {            // 1 head spans both wc halves
                as[m * NH + hb] = sAs[t * 2] + sAs[t * 2 + 1];
                ad[m * NH + hb] = sAd[t * 2] + sAd[t * 2 + 1];
            } else {                       // wc half = head
                as[m * NH + hb]     = sAs[t * 2];
                as[m * NH + hb + 1] = sAs[t * 2 + 1];
                ad[m * NH + hb]     = sAd[t * 2];
                ad[m * NH + hb + 1] = sAd[t * 2 + 1];
            }
        }
    }
}

// ---------------- CSR scan/fill ----------------
// single-pass chunked exclusive scan of (counts[i] + 1); the +1 is the self-loop
__global__ void k_scan(const int* __restrict__ counts, int* rowptr, int* cursor, int n) {
    __shared__ int s[1024];
    int t = threadIdx.x;
    const int CH = (NN + 1023) / 1024;     // 10
    int base = t * CH;
    int loc[CH];
    int sum = 0;
#pragma unroll
    for (int i = 0; i < CH; i++) {
        int idx = base + i;
        int v = (idx < n) ? (counts[idx] + 1) : 0;
        loc[i] = sum;
        sum += v;
    }
    s[t] = sum;
    __syncthreads();
    for (int off = 1; off < 1024; off <<= 1) {
        int add = (t >= off) ? s[t - off] : 0;
        __syncthreads();
        s[t] += add;
        __syncthreads();
    }
    int pre = (t > 0) ? s[t - 1] : 0;
#pragma unroll
    for (int i = 0; i < CH; i++) {
        int idx = base + i;
        if (idx < n) { int ex = pre + loc[i]; rowptr[idx] = ex; cursor[idx] = ex; }
    }
    if (t == 1023) rowptr[n] = s[1023];
}
__global__ void k_csr_fill(const int* __restrict__ ei, int* cursor, int* colidx, int E, int n) {
    int i = blockIdx.x * 256 + threadIdx.x;
    if (i >= E + n) return;
    int s, d;
    if (i < E) { s = ei[i]; d = ei[E + i]; }
    else       { s = i - E; d = i - E; }
    int pos = atomicAdd(&cursor[d], 1);
    colidx[pos] = s;
}

// ---------------- layer-1: FUSED softmax + wide-row aggregation -> A2 fp16 ----------------
// 320 threads. Softmax: wave w computes alpha for heads 2w,2w+1 into LDS.
// Gather: thread t owns channels 4t..4t+3 (head = t>>5), f16x4 row gather,
// j-loop unrolled x4 for 4 loads in flight (MLP). grid = MP: pad rows write zeros.
__global__ __launch_bounds__(320) void k_agg1(const int* __restrict__ rowptr,
                                              const int* __restrict__ colidx,
                                              const float* __restrict__ as,
                                              const float* __restrict__ ad,
                                              const _Float16* __restrict__ h,
                                              const float* __restrict__ bias,
                                              _Float16* __restrict__ A2) {
    __shared__ int sidx[64];
    __shared__ float sal[64 * NH];
    int n = blockIdx.x, t = threadIdx.x;
    if (n >= NN) {
        f16x4 z = {(_Float16)0.f, (_Float16)0.f, (_Float16)0.f, (_Float16)0.f};
        *(f16x4*)(A2 + (long)n * HC1 + 4 * t) = z;
        return;
    }
    int k0 = rowptr[n], deg = rowptr[n + 1] - k0;
    int w = t >> 6, lane = t & 63;
    int hd = t >> 5;
    float acc[4] = {0, 0, 0, 0};

    if (deg <= 64) {
        int src = (lane < deg) ? colidx[k0 + lane] : 0;
        float2 adv = *(const float2*)(ad + n * NH + 2 * w);
        float e0 = -1e30f, e1 = -1e30f;
        if (lane < deg) {
            float2 avv = *(const float2*)(as + (long)src * NH + 2 * w);
            e0 = leaky(avv.x + adv.x);
            e1 = leaky(avv.y + adv.y);
        }
        float m0 = e0, m1 = e1;
        for (int m = 32; m; m >>= 1) {
            m0 = fmaxf(m0, __shfl_xor(m0, m));
            m1 = fmaxf(m1, __shfl_xor(m1, m));
        }
        float x0 = (lane < deg) ? __expf(e0 - m0) : 0.f;
        float x1 = (lane < deg) ? __expf(e1 - m1) : 0.f;
        float s0 = x0, s1 = x1;
        for (int m = 32; m; m >>= 1) {
            s0 += __shfl_xor(s0, m);
            s1 += __shfl_xor(s1, m);
        }
        if (lane < deg) {
            sal[lane * NH + 2 * w]     = x0 / (s0 + 1e-16f);
            sal[lane * NH + 2 * w + 1] = x1 / (s1 + 1e-16f);
            if (w == 0) sidx[lane] = src;
        }
        __syncthreads();
        int j = 0;
        for (; j + 4 <= deg; j += 4) {            // 4 loads in flight
            int sj0 = sidx[j], sj1 = sidx[j + 1], sj2 = sidx[j + 2], sj3 = sidx[j + 3];
            float a0 = sal[j * NH + hd], a1 = sal[(j + 1) * NH + hd];
            float a2 = sal[(j + 2) * NH + hd], a3 = sal[(j + 3) * NH + hd];
            f16x4 v0 = *(const f16x4*)(h + (long)sj0 * HC1 + 4 * t);
            f16x4 v1 = *(const f16x4*)(h + (long)sj1 * HC1 + 4 * t);
            f16x4 v2 = *(const f16x4*)(h + (long)sj2 * HC1 + 4 * t);
            f16x4 v3 = *(const f16x4*)(h + (long)sj3 * HC1 + 4 * t);
#pragma unroll
            for (int i = 0; i < 4; i++)
                acc[i] += a0 * (float)v0[i] + a1 * (float)v1[i]
                        + a2 * (float)v2[i] + a3 * (float)v3[i];
        }
        for (; j < deg; j++) {
            int src2 = sidx[j];
            float a = sal[j * NH + hd];
            f16x4 v = *(const f16x4*)(h + (long)src2 * HC1 + 4 * t);
#pragma unroll
            for (int i = 0; i < 4; i++) acc[i] += a * (float)v[i];
        }
    } else {
        float2 adv = *(const float2*)(ad + n * NH + 2 * w);
        float m0 = -1e30f, m1 = -1e30f;
        for (int j = lane; j < deg; j += 64) {
            float2 avv = *(const float2*)(as + (long)colidx[k0 + j] * NH + 2 * w);
            m0 = fmaxf(m0, leaky(avv.x + adv.x));
            m1 = fmaxf(m1, leaky(avv.y + adv.y));
        }
        for (int m = 32; m; m >>= 1) {
            m0 = fmaxf(m0, __shfl_xor(m0, m));
            m1 = fmaxf(m1, __shfl_xor(m1, m));
        }
        float s0 = 0.f, s1 = 0.f;
        for (int j = lane; j < deg; j += 64) {
            float2 avv = *(const float2*)(as + (long)colidx[k0 + j] * NH + 2 * w);
            s0 += __expf(leaky(avv.x + adv.x) - m0);
            s1 += __expf(leaky(avv.y + adv.y) - m1);
        }
        for (int m = 32; m; m >>= 1) {
            s0 += __shfl_xor(s0, m);
            s1 += __shfl_xor(s1, m);
        }
        float i0 = 1.f / (s0 + 1e-16f), i1 = 1.f / (s1 + 1e-16f);
        for (int c0 = 0; c0 < deg; c0 += 64) {
            int cn = min(64, deg - c0);
            __syncthreads();
            if (lane < cn) {
                int src = colidx[k0 + c0 + lane];
                float2 avv = *(const float2*)(as + (long)src * NH + 2 * w);
                sal[lane * NH + 2 * w]     = __expf(leaky(avv.x + adv.x) - m0) * i0;
                sal[lane * NH + 2 * w + 1] = __expf(leaky(avv.y + adv.y) - m1) * i1;
                if (w == 0) sidx[lane] = src;
            }
            __syncthreads();
            for (int j = 0; j < cn; j++) {
                int src2 = sidx[j];
                float a = sal[j * NH + hd];
                f16x4 v = *(const f16x4*)(h + (long)src2 * HC1 + 4 * t);
#pragma unroll
                for (int i = 0; i < 4; i++) acc[i] += a * (float)v[i];
            }
        }
    }
    f16x4 o;
#pragma unroll
    for (int i = 0; i < 4; i++) {
        float x = acc[i] + bias[4 * t + i];
        o[i] = (_Float16)(x > 0.f ? x : 0.f);
    }
    *(f16x4*)(A2 + (long)n * HC1 + 4 * t) = o;
}

// ---------------- layer-2: FUSED softmax + aggregation + head mean + bias + relu ----------------
__global__ __launch_bounds__(320) void k_agg2(const int* __restrict__ rowptr,
                                              const int* __restrict__ colidx,
                                              const float* __restrict__ as,
                                              const float* __restrict__ ad,
                                              const _Float16* __restrict__ h,
                                              const float* __restrict__ bias,
                                              float* __restrict__ out) {
    __shared__ int sidx[64];
    __shared__ float sal[64 * NH];
    __shared__ float facc[HC2];
    int n = blockIdx.x, t = threadIdx.x;
    int k0 = rowptr[n], deg = rowptr[n + 1] - k0;
    int w = t >> 6, lane = t & 63;
    int hd = t >> 5;
    float a0 = 0.f, a1 = 0.f;

    if (deg <= 64) {
        int src = (lane < deg) ? colidx[k0 + lane] : 0;
        float2 adv = *(const float2*)(ad + n * NH + 2 * w);
        float e0 = -1e30f, e1 = -1e30f;
        if (lane < deg) {
            float2 avv = *(const float2*)(as + (long)src * NH + 2 * w);
            e0 = leaky(avv.x + adv.x);
            e1 = leaky(avv.y + adv.y);
        }
        float m0 = e0, m1 = e1;
        for (int m = 32; m; m >>= 1) {
            m0 = fmaxf(m0, __shfl_xor(m0, m));
            m1 = fmaxf(m1, __shfl_xor(m1, m));
        }
        float x0 = (lane < deg) ? __expf(e0 - m0) : 0.f;
        float x1 = (lane < deg) ? __expf(e1 - m1) : 0.f;
        float s0 = x0, s1 = x1;
        for (int m = 32; m; m >>= 1) {
            s0 += __shfl_xor(s0, m);
            s1 += __shfl_xor(s1, m);
        }
        if (lane < deg) {
            sal[lane * NH + 2 * w]     = x0 / (s0 + 1e-16f);
            sal[lane * NH + 2 * w + 1] = x1 / (s1 + 1e-16f);
            if (w == 0) sidx[lane] = src;
        }
        __syncthreads();
        int j = 0;
        for (; j + 4 <= deg; j += 4) {            // 4 loads in flight
            int sj0 = sidx[j], sj1 = sidx[j + 1], sj2 = sidx[j + 2], sj3 = sidx[j + 3];
            float b0 = sal[j * NH + hd], b1 = sal[(j + 1) * NH + hd];
            float b2 = sal[(j + 2) * NH + hd], b3 = sal[(j + 3) * NH + hd];
            f16x2 v0 = *(const f16x2*)(h + (long)sj0 * HC2 + 2 * t);
            f16x2 v1 = *(const f16x2*)(h + (long)sj1 * HC2 + 2 * t);
            f16x2 v2 = *(const f16x2*)(h + (long)sj2 * HC2 + 2 * t);
            f16x2 v3 = *(const f16x2*)(h + (long)sj3 * HC2 + 2 * t);
            a0 += b0 * (float)v0[0] + b1 * (float)v1[0] + b2 * (float)v2[0] + b3 * (float)v3[0];
            a1 += b0 * (float)v0[1] + b1 * (float)v1[1] + b2 * (float)v2[1] + b3 * (float)v3[1];
        }
        for (; j < deg; j++) {
            int src2 = sidx[j];
            float a = sal[j * NH + hd];
            f16x2 v = *(const f16x2*)(h + (long)src2 * HC2 + 2 * t);
            a0 += a * (float)v[0];
            a1 += a * (float)v[1];
        }
    } else {
        float2 adv = *(const float2*)(ad + n * NH + 2 * w);
        float m0 = -1e30f, m1 = -1e30f;
        for (int j = lane; j < deg; j += 64) {
            float2 avv = *(const float2*)(as + (long)colidx[k0 + j] * NH + 2 * w);
            m0 = fmaxf(m0, leaky(avv.x + adv.x));
            m1 = fmaxf(m1, leaky(avv.y + adv.y));
        }
        for (int m = 32; m; m >>= 1) {
            m0 = fmaxf(m0, __shfl_xor(m0, m));
            m1 = fmaxf(m1, __shfl_xor(m1, m));
        }
        float s0 = 0.f, s1 = 0.f;
        for (int j = lane; j < deg; j += 64) {
            float2 avv = *(const float2*)(as + (long)colidx[k0 + j] * NH + 2 * w);
            s0 += __expf(leaky(avv.x + adv.x) - m0);
            s1 += __expf(leaky(avv.y + adv.y) - m1);
        }
        for (int m = 32; m; m >>= 1) {
            s0 += __shfl_xor(s0, m);
            s1 += __shfl_xor(s1, m);
        }
        float i0 = 1.f / (s0 + 1e-16f), i1 = 1.f / (s1 + 1e-16f);
        for (int c0 = 0; c0 < deg; c0 += 64) {
            int cn = min(64, deg - c0);
            __syncthreads();
            if (lane < cn) {
                int src = colidx[k0 + c0 + lane];
                float2 avv = *(const float2*)(as + (long)src * NH + 2 * w);
                sal[lane * NH + 2 * w]     = __expf(leaky(avv.x + adv.x) - m0) * i0;
                sal[lane * NH + 2 * w + 1] = __expf(leaky(avv.y + adv.y) - m1) * i1;
                if (w == 0) sidx[lane] = src;
            }
            __syncthreads();
            for (int j = 0; j < cn; j++) {
                int src2 = sidx[j];
                float a = sal[j * NH + hd];
                f16x2 v = *(const f16x2*)(h + (long)src2 * HC2 + 2 * t);
                a0 += a * (float)v[0];
                a1 += a * (float)v[1];
            }
        }
    }
    facc[2 * t] = a0;
    facc[2 * t + 1] = a1;
    __syncthreads();
    if (t < C2) {
        float s = 0.f;
#pragma unroll
        for (int hh = 0; hh < NH; hh++) s += facc[hh * C2 + t];
        s = s * 0.1f + bias[t];
        out[(long)n * C2 + t] = s > 0.f ? s : 0.f;
    }
}

// ---------------- host ----------------
extern "C" void kernel_launch(void* const* d_in, const int* in_sizes, int n_in,
                              void* d_out, int out_size, void* d_ws, size_t ws_size,
                              hipStream_t stream) {
    const float* x      = (const float*)d_in[0];
    const int*   ei     = (const int*)d_in[1];
    const float* W1     = (const float*)d_in[2];
    const float* asrc1  = (const float*)d_in[3];
    const float* adst1  = (const float*)d_in[4];
    const float* b1     = (const float*)d_in[5];
    const float* W2     = (const float*)d_in[6];
    const float* asrc2  = (const float*)d_in[7];
    const float* adst2  = (const float*)d_in[8];
    const float* b2     = (const float*)d_in[9];
    float* out = (float*)d_out;
    const int E  = in_sizes[1] / 2;
    const int EN = E + NN;

    char* base = (char*)d_ws;
    size_t o = 0;
    auto alloc = [&](size_t bytes) { size_t r = o; o += (bytes + 255) & ~(size_t)255; return r; };
    _Float16* A1    = (_Float16*)(base + alloc((size_t)MP * K1P * 2));
    _Float16* W1t   = (_Float16*)(base + alloc((size_t)HC1 * K1P * 2));
    _Float16* A2    = (_Float16*)(base + alloc((size_t)MP * HC1 * 2));
    _Float16* W2t   = (_Float16*)(base + alloc((size_t)HC2 * HC1 * 2));
    _Float16* h1pre = (_Float16*)(base + alloc((size_t)MP * HC1 * 2));
    _Float16* h2pre = (_Float16*)(base + alloc((size_t)MP * HC2 * 2));
    float* as1      = (float*)(base + alloc((size_t)NN * NH * 4));
    float* ad1      = (float*)(base + alloc((size_t)NN * NH * 4));
    float* as2      = (float*)(base + alloc((size_t)NN * NH * 4));
    float* ad2      = (float*)(base + alloc((size_t)NN * NH * 4));
    int* counts     = (int*)(base + alloc((size_t)(NN + 1) * 4));
    int* rowptr     = (int*)(base + alloc((size_t)(NN + 1) * 4));
    int* cursor     = (int*)(base + alloc((size_t)(NN + 1) * 4));
    int* colidx     = (int*)(base + alloc((size_t)EN * 4));
    (void)ws_size; (void)n_in; (void)out_size;

    // ---- transposes (both W) + zero counts ----
    k_transpose_both<<<dim3(63, 60), 256, 0, stream>>>(W1, W1t, W2, W2t, counts);
    // ---- cast x -> A1 fp16 + CSR edge count (counts zeroed above) ----
    k_cast_count<<<dim3(2, MP), 256, 0, stream>>>(x, A1, NN, FIN / 4, K1P / 4, ei, counts, E);
    // ---- layer 1 GEMM (+ fused logits) ----
    k_gemm<<<8 * (MP / 256 / 8) * (HC1 / 128), 256, 0, stream>>>(A1, W1t, h1pre, K1P, HC1, HC1 / 128,
                                                                 asrc1, adst1, as1, ad1, C1);
    // ---- CSR scan + fill ----
    k_scan<<<1, 1024, 0, stream>>>(counts, rowptr, cursor, NN);
    k_csr_fill<<<(EN + 255) / 256, 256, 0, stream>>>(ei, cursor, colidx, E, NN);
    // ---- layer 1: fused softmax/aggregate -> A2 (pad rows zeroed inside) ----
    k_agg1<<<MP, 320, 0, stream>>>(rowptr, colidx, as1, ad1, h1pre, b1, A2);
    // ---- layer 2 GEMM (+ fused logits) ----
    k_gemm<<<8 * (MP / 256 / 8) * (HC2 / 128), 256, 0, stream>>>(A2, W2t, h2pre, HC1, HC2, HC2 / 128,
                                                                 asrc2, adst2, as2, ad2, C2);
    // ---- layer 2: fused softmax/aggregate + head mean ----
    k_agg2<<<NN, 320, 0, stream>>>(rowptr, colidx, as2, ad2, h2pre, b2, out);
}

// Round 11
// 363.192 us; speedup vs baseline: 1.3406x; 1.0444x over previous
//
#include <hip/hip_runtime.h>

// ---------------- problem constants ----------------
#define NN    10000          // nodes
#define FIN   2000           // input features
#define NH    10             // heads
#define C1    128            // layer-1 out channels per head
#define C2    64             // layer-2 out channels per head
#define HC1   1280           // NH*C1
#define HC2   640            // NH*C2
#define MP    10240          // nodes padded to 256*40
#define K1P   2016           // FIN padded to 32 multiple (63*32)

typedef _Float16 f16x8 __attribute__((ext_vector_type(8)));
typedef _Float16 f16x4 __attribute__((ext_vector_type(4)));
typedef _Float16 f16x2 __attribute__((ext_vector_type(2)));
typedef float    f32x4 __attribute__((ext_vector_type(4)));

__device__ __forceinline__ float leaky(float x) { return x > 0.f ? x : 0.2f * x; }

// ---------------- fused prep: cast x->fp16, transpose W1, transpose W2, edge count ----------------
// counts must be zeroed by a prior memset. 1-D grid partitioned by role.
#define NCAST (2 * MP)        // 2 blocks per row (Cp4=504)
#define NW1   (63 * 40)
#define NW2   (40 * 20)
__global__ void k_prep(const float* __restrict__ x, _Float16* __restrict__ A1,
                       const float* __restrict__ W1, _Float16* __restrict__ W1t,
                       const float* __restrict__ W2, _Float16* __restrict__ W2t,
                       const int* __restrict__ ei, int* __restrict__ counts, int E) {
    __shared__ float tile[32][33];
    int bid = blockIdx.x, t = threadIdx.x;
    if (bid < NCAST) {
        int r = bid >> 1;
        int c = (bid & 1) * 256 + t;
        if (c >= K1P / 4) return;
        float4 v = make_float4(0.f, 0.f, 0.f, 0.f);
        if (r < NN && c < FIN / 4) v = *(const float4*)(x + (long)r * FIN + 4 * c);
        f16x4 o = {(_Float16)v.x, (_Float16)v.y, (_Float16)v.z, (_Float16)v.w};
        *(f16x4*)(A1 + (long)r * K1P + 4 * c) = o;
        return;
    }
    const float* W; _Float16* Wt; int K, N, Kpad, kbase, nbase;
    if (bid < NCAST + NW1) {
        int i = bid - NCAST;
        W = W1; Wt = W1t; K = FIN; N = HC1; Kpad = K1P;
        kbase = (i % 63) * 32; nbase = (i / 63) * 32;
    } else if (bid < NCAST + NW1 + NW2) {
        int i = bid - NCAST - NW1;
        W = W2; Wt = W2t; K = HC1; N = HC2; Kpad = HC1;
        kbase = (i % 40) * 32; nbase = (i / 40) * 32;
    } else {
        int e = (bid - NCAST - NW1 - NW2) * 256 + t;
        if (e < E) atomicAdd(&counts[ei[E + e]], 1);
        return;
    }
    int tx = t & 31, ty = t >> 5;
#pragma unroll
    for (int i = 0; i < 4; i++) {
        int k = kbase + ty + i * 8;
        float v = (k < K) ? W[(long)k * N + nbase + tx] : 0.0f;
        tile[ty + i * 8][tx] = v;
    }
    __syncthreads();
#pragma unroll
    for (int i = 0; i < 4; i++) {
        int n = nbase + ty + i * 8;
        Wt[(long)n * Kpad + kbase + tx] = (_Float16)tile[tx][ty + i * 8];
    }
}

// ---------------- async global->LDS helper ----------------
__device__ __forceinline__ void gl2lds16(const void* g, void* l) {
    __builtin_amdgcn_global_load_lds((const __attribute__((address_space(1))) void*)g,
                                     (__attribute__((address_space(3))) void*)l, 16, 0, 0);
}

// ---------------- fp16 MFMA GEMM + fused attention logits + optional CSR-fill side-job ----------------
// C[MpxN](fp16) = A[MpxK] * Bt[NxK]^T. BM=32*MFRAG x BN=128, 4 waves (2x2), wave
// tile (16*MFRAG)x64. Tri-buffered LDS, raw s_barrier + fine-grained s_waitcnt
// (stage for k+1 stays in flight across barriers). Epilogue computes as/ad
// logits from the fp32 acc. Blocks with bid >= nblk do CSR fill instead.
template<int MFRAG>
__global__ __launch_bounds__(256, 2) void k_gemm(const _Float16* __restrict__ A,
                                                 const _Float16* __restrict__ Bt,
                                                 _Float16* __restrict__ C, int K, int N,
                                                 int NTN,
                                                 const float* __restrict__ asf,
                                                 const float* __restrict__ adf,
                                                 float* __restrict__ as,
                                                 float* __restrict__ ad,
                                                 int headw, int nblk,
                                                 const int* __restrict__ ei,
                                                 int* __restrict__ cursor,
                                                 int* __restrict__ colidx, int E) {
    constexpr int BM   = MFRAG * 32;
    constexpr int ABUF = BM * 32;               // fp16 elems per A buffer
    constexpr int ASL  = BM / 64;               // A staging slots per thread
    constexpr int WVM  = 0x0F70 | (ASL + 2);    // vmcnt <= loads-per-stage
    __shared__ char smem[3 * ABUF * 2 + 3 * 8192] __attribute__((aligned(16)));
    _Float16* As = (_Float16*)smem;
    _Float16* Bs = (_Float16*)(smem + 3 * ABUF * 2);

    int bid = blockIdx.x;
    if (bid >= nblk) {                          // CSR fill side-job
        int i = (bid - nblk) * 256 + threadIdx.x;
        if (i < E + NN) {
            int s, d;
            if (i < E) { s = ei[i]; d = ei[E + i]; }
            else       { s = i - E; d = i - E; }
            int pos = atomicAdd(&cursor[d], 1);
            colidx[pos] = s;
        }
        return;
    }
    int r = bid & 7, qb = bid >> 3;
    int n_t = qb % NTN;
    int m_t = r + 8 * (qb / NTN);
    int m0 = m_t * BM;
    int n0 = n_t * 128;
    int t = threadIdx.x;
    int lane = t & 63, wave = t >> 6;
    int wr = wave >> 1, wc = wave & 1;
    int lrow = lane & 15, q = lane >> 4;

    f32x4 acc[MFRAG][4] = {};

    int sA[ASL], sB[2];
#pragma unroll
    for (int i = 0; i < ASL; i++) sA[i] = t + 256 * i;
#pragma unroll
    for (int i = 0; i < 2; i++) sB[i] = t + 256 * i;
    const _Float16* Ar[ASL];
    const _Float16* Br[2];
#pragma unroll
    for (int i = 0; i < ASL; i++) {
        int row = sA[i] >> 2, gq = (sA[i] & 3) ^ ((sA[i] >> 3) & 3);
        Ar[i] = A + (long)(m0 + row) * K + gq * 8;
    }
#pragma unroll
    for (int i = 0; i < 2; i++) {
        int row = sB[i] >> 2, gq = (sB[i] & 3) ^ ((sB[i] >> 3) & 3);
        Br[i] = Bt + (long)(n0 + row) * K + gq * 8;
    }

    int aoff[MFRAG], boff[4];
#pragma unroll
    for (int i = 0; i < MFRAG; i++) {
        int rowa = wr * (MFRAG * 16) + i * 16 + lrow;
        aoff[i] = rowa * 32 + ((q ^ ((rowa >> 1) & 3)) << 3);
    }
#pragma unroll
    for (int i = 0; i < 4; i++) {
        int rowb = wc * 64 + i * 16 + lrow;
        boff[i] = rowb * 32 + ((q ^ ((rowb >> 1) & 3)) << 3);
    }

    auto stage = [&](int it, int buf) {
        int k0 = it << 5;
#pragma unroll
        for (int i = 0; i < ASL; i++) gl2lds16(Ar[i] + k0, &As[buf * ABUF + sA[i] * 8]);
#pragma unroll
        for (int i = 0; i < 2; i++) gl2lds16(Br[i] + k0, &Bs[buf * 4096 + sB[i] * 8]);
    };

    int nk = K >> 5;
    stage(0, 0);
    stage(1, 1);
    int cur = 0;
    for (int it = 0; it < nk; it++) {
        if (it + 1 < nk) __builtin_amdgcn_s_waitcnt(WVM);
        else             __builtin_amdgcn_s_waitcnt(0x0F70);
        __builtin_amdgcn_s_barrier();
        int nxt = cur + 2; if (nxt >= 3) nxt -= 3;
        if (it + 2 < nk) stage(it + 2, nxt);

        f16x8 af[MFRAG], bf[4];
#pragma unroll
        for (int i = 0; i < MFRAG; i++) af[i] = *(const f16x8*)&As[cur * ABUF + aoff[i]];
#pragma unroll
        for (int i = 0; i < 4; i++) bf[i] = *(const f16x8*)&Bs[cur * 4096 + boff[i]];
#pragma unroll
        for (int mt = 0; mt < MFRAG; mt++)
#pragma unroll
            for (int nt = 0; nt < 4; nt++)
                acc[mt][nt] = __builtin_amdgcn_mfma_f32_16x16x32_f16(bf[nt], af[mt], acc[mt][nt], 0, 0, 0);
        cur = (cur + 1 == 3) ? 0 : cur + 1;
    }

    // ---- C store: lane holds C[m][n..n+3] per fragment -> packed 8B stores ----
#pragma unroll
    for (int mt = 0; mt < MFRAG; mt++) {
        int m = m0 + wr * (MFRAG * 16) + mt * 16 + lrow;
#pragma unroll
        for (int nt = 0; nt < 4; nt++) {
            int n = n0 + wc * 64 + nt * 16 + q * 4;
            f16x4 o = {(_Float16)acc[mt][nt][0], (_Float16)acc[mt][nt][1],
                       (_Float16)acc[mt][nt][2], (_Float16)acc[mt][nt][3]};
            *(f16x4*)(C + (long)m * N + n) = o;
        }
    }

    // ---- fused logits: as/ad = h-row . asf/adf per head ----
    float4 av[4], dvv[4];
#pragma unroll
    for (int nt = 0; nt < 4; nt++) {
        av[nt]  = *(const float4*)(asf + n0 + wc * 64 + nt * 16 + q * 4);
        dvv[nt] = *(const float4*)(adf + n0 + wc * 64 + nt * 16 + q * 4);
    }
    __syncthreads();                       // done reading As/Bs; reuse smem
    float* sAs = (float*)smem;             // BM*2 floats
    float* sAd = (float*)smem + BM * 2;
#pragma unroll
    for (int mt = 0; mt < MFRAG; mt++) {
        float ps = 0.f, pd = 0.f;
#pragma unroll
        for (int nt = 0; nt < 4; nt++) {
            ps += acc[mt][nt][0] * av[nt].x + acc[mt][nt][1] * av[nt].y
                + acc[mt][nt][2] * av[nt].z + acc[mt][nt][3] * av[nt].w;
            pd += acc[mt][nt][0] * dvv[nt].x + acc[mt][nt][1] * dvv[nt].y
                + acc[mt][nt][2] * dvv[nt].z + acc[mt][nt][3] * dvv[nt].w;
        }
        ps += __shfl_xor(ps, 16); ps += __shfl_xor(ps, 32);   // reduce over q lanes
        pd += __shfl_xor(pd, 16); pd += __shfl_xor(pd, 32);
        if (q == 0) {
            int rl = wr * (MFRAG * 16) + mt * 16 + lrow;
            sAs[rl * 2 + wc] = ps;
            sAd[rl * 2 + wc] = pd;
        }
    }
    __syncthreads();
    if (t < BM) {
        int m = m0 + t;
        if (m < NN) {
            int hb = n0 / headw;
            if (headw == 128) {            // 1 head spans both wc halves
                as[m * NH + hb] = sAs[t * 2] + sAs[t * 2 + 1];
                ad[m * NH + hb] = sAd[t * 2] + sAd[t * 2 + 1];
            } else {                       // wc half = head
                as[m * NH + hb]     = sAs[t * 2];
                as[m * NH + hb + 1] = sAs[t * 2 + 1];
                ad[m * NH + hb]     = sAd[t * 2];
                ad[m * NH + hb + 1] = sAd[t * 2 + 1];
            }
        }
    }
}

// ---------------- CSR scan: single-pass chunked exclusive scan of (counts[i]+1) ----------------
__global__ void k_scan(const int* __restrict__ counts, int* rowptr, int* cursor, int n) {
    __shared__ int s[1024];
    int t = threadIdx.x;
    const int CH = (NN + 1023) / 1024;     // 10
    int base = t * CH;
    int loc[CH];
    int sum = 0;
#pragma unroll
    for (int i = 0; i < CH; i++) {
        int idx = base + i;
        int v = (idx < n) ? (counts[idx] + 1) : 0;
        loc[i] = sum;
        sum += v;
    }
    s[t] = sum;
    __syncthreads();
    for (int off = 1; off < 1024; off <<= 1) {
        int add = (t >= off) ? s[t - off] : 0;
        __syncthreads();
        s[t] += add;
        __syncthreads();
    }
    int pre = (t > 0) ? s[t - 1] : 0;
#pragma unroll
    for (int i = 0; i < CH; i++) {
        int idx = base + i;
        if (idx < n) { int ex = pre + loc[i]; rowptr[idx] = ex; cursor[idx] = ex; }
    }
    if (t == 1023) rowptr[n] = s[1023];
}

// ---------------- layer-1: FUSED softmax + wide-row aggregation -> A2 fp16 ----------------
__global__ __launch_bounds__(320) void k_agg1(const int* __restrict__ rowptr,
                                              const int* __restrict__ colidx,
                                              const float* __restrict__ as,
                                              const float* __restrict__ ad,
                                              const _Float16* __restrict__ h,
                                              const float* __restrict__ bias,
                                              _Float16* __restrict__ A2) {
    __shared__ int sidx[64];
    __shared__ float sal[64 * NH];
    int n = blockIdx.x, t = threadIdx.x;
    if (n >= NN) {
        f16x4 z = {(_Float16)0.f, (_Float16)0.f, (_Float16)0.f, (_Float16)0.f};
        *(f16x4*)(A2 + (long)n * HC1 + 4 * t) = z;
        return;
    }
    int k0 = rowptr[n], deg = rowptr[n + 1] - k0;
    int w = t >> 6, lane = t & 63;
    int hd = t >> 5;
    float acc[4] = {0, 0, 0, 0};

    if (deg <= 64) {
        int src = (lane < deg) ? colidx[k0 + lane] : 0;
        float2 adv = *(const float2*)(ad + n * NH + 2 * w);
        float e0 = -1e30f, e1 = -1e30f;
        if (lane < deg) {
            float2 avv = *(const float2*)(as + (long)src * NH + 2 * w);
            e0 = leaky(avv.x + adv.x);
            e1 = leaky(avv.y + adv.y);
        }
        float m0 = e0, m1 = e1;
        for (int m = 32; m; m >>= 1) {
            m0 = fmaxf(m0, __shfl_xor(m0, m));
            m1 = fmaxf(m1, __shfl_xor(m1, m));
        }
        float x0 = (lane < deg) ? __expf(e0 - m0) : 0.f;
        float x1 = (lane < deg) ? __expf(e1 - m1) : 0.f;
        float s0 = x0, s1 = x1;
        for (int m = 32; m; m >>= 1) {
            s0 += __shfl_xor(s0, m);
            s1 += __shfl_xor(s1, m);
        }
        if (lane < deg) {
            sal[lane * NH + 2 * w]     = x0 / (s0 + 1e-16f);
            sal[lane * NH + 2 * w + 1] = x1 / (s1 + 1e-16f);
            if (w == 0) sidx[lane] = src;
        }
        __syncthreads();
        int j = 0;
        for (; j + 4 <= deg; j += 4) {            // 4 loads in flight
            int sj0 = sidx[j], sj1 = sidx[j + 1], sj2 = sidx[j + 2], sj3 = sidx[j + 3];
            float a0 = sal[j * NH + hd], a1 = sal[(j + 1) * NH + hd];
            float a2 = sal[(j + 2) * NH + hd], a3 = sal[(j + 3) * NH + hd];
            f16x4 v0 = *(const f16x4*)(h + (long)sj0 * HC1 + 4 * t);
            f16x4 v1 = *(const f16x4*)(h + (long)sj1 * HC1 + 4 * t);
            f16x4 v2 = *(const f16x4*)(h + (long)sj2 * HC1 + 4 * t);
            f16x4 v3 = *(const f16x4*)(h + (long)sj3 * HC1 + 4 * t);
#pragma unroll
            for (int i = 0; i < 4; i++)
                acc[i] += a0 * (float)v0[i] + a1 * (float)v1[i]
                        + a2 * (float)v2[i] + a3 * (float)v3[i];
        }
        for (; j < deg; j++) {
            int src2 = sidx[j];
            float a = sal[j * NH + hd];
            f16x4 v = *(const f16x4*)(h + (long)src2 * HC1 + 4 * t);
#pragma unroll
            for (int i = 0; i < 4; i++) acc[i] += a * (float)v[i];
        }
    } else {
        float2 adv = *(const float2*)(ad + n * NH + 2 * w);
        float m0 = -1e30f, m1 = -1e30f;
        for (int j = lane; j < deg; j += 64) {
            float2 avv = *(const float2*)(as + (long)colidx[k0 + j] * NH + 2 * w);
            m0 = fmaxf(m0, leaky(avv.x + adv.x));
            m1 = fmaxf(m1, leaky(avv.y + adv.y));
        }
        for (int m = 32; m; m >>= 1) {
            m0 = fmaxf(m0, __shfl_xor(m0, m));
            m1 = fmaxf(m1, __shfl_xor(m1, m));
        }
        float s0 = 0.f, s1 = 0.f;
        for (int j = lane; j < deg; j += 64) {
            float2 avv = *(const float2*)(as + (long)colidx[k0 + j] * NH + 2 * w);
            s0 += __expf(leaky(avv.x + adv.x) - m0);
            s1 += __expf(leaky(avv.y + adv.y) - m1);
        }
        for (int m = 32; m; m >>= 1) {
            s0 += __shfl_xor(s0, m);
            s1 += __shfl_xor(s1, m);
        }
        float i0 = 1.f / (s0 + 1e-16f), i1 = 1.f / (s1 + 1e-16f);
        for (int c0 = 0; c0 < deg; c0 += 64) {
            int cn = min(64, deg - c0);
            __syncthreads();
            if (lane < cn) {
                int src = colidx[k0 + c0 + lane];
                float2 avv = *(const float2*)(as + (long)src * NH + 2 * w);
                sal[lane * NH + 2 * w]     = __expf(leaky(avv.x + adv.x) - m0) * i0;
                sal[lane * NH + 2 * w + 1] = __expf(leaky(avv.y + adv.y) - m1) * i1;
                if (w == 0) sidx[lane] = src;
            }
            __syncthreads();
            for (int j = 0; j < cn; j++) {
                int src2 = sidx[j];
                float a = sal[j * NH + hd];
                f16x4 v = *(const f16x4*)(h + (long)src2 * HC1 + 4 * t);
#pragma unroll
                for (int i = 0; i < 4; i++) acc[i] += a * (float)v[i];
            }
        }
    }
    f16x4 o;
#pragma unroll
    for (int i = 0; i < 4; i++) {
        float x = acc[i] + bias[4 * t + i];
        o[i] = (_Float16)(x > 0.f ? x : 0.f);
    }
    *(f16x4*)(A2 + (long)n * HC1 + 4 * t) = o;
}

// ---------------- layer-2: FUSED softmax + aggregation + head mean + bias + relu ----------------
__global__ __launch_bounds__(320) void k_agg2(const int* __restrict__ rowptr,
                                              const int* __restrict__ colidx,
                                              const float* __restrict__ as,
                                              const float* __restrict__ ad,
                                              const _Float16* __restrict__ h,
                                              const float* __restrict__ bias,
                                              float* __restrict__ out) {
    __shared__ int sidx[64];
    __shared__ float sal[64 * NH];
    __shared__ float facc[HC2];
    int n = blockIdx.x, t = threadIdx.x;
    int k0 = rowptr[n], deg = rowptr[n + 1] - k0;
    int w = t >> 6, lane = t & 63;
    int hd = t >> 5;
    float a0 = 0.f, a1 = 0.f;

    if (deg <= 64) {
        int src = (lane < deg) ? colidx[k0 + lane] : 0;
        float2 adv = *(const float2*)(ad + n * NH + 2 * w);
        float e0 = -1e30f, e1 = -1e30f;
        if (lane < deg) {
            float2 avv = *(const float2*)(as + (long)src * NH + 2 * w);
            e0 = leaky(avv.x + adv.x);
            e1 = leaky(avv.y + adv.y);
        }
        float m0 = e0, m1 = e1;
        for (int m = 32; m; m >>= 1) {
            m0 = fmaxf(m0, __shfl_xor(m0, m));
            m1 = fmaxf(m1, __shfl_xor(m1, m));
        }
        float x0 = (lane < deg) ? __expf(e0 - m0) : 0.f;
        float x1 = (lane < deg) ? __expf(e1 - m1) : 0.f;
        float s0 = x0, s1 = x1;
        for (int m = 32; m; m >>= 1) {
            s0 += __shfl_xor(s0, m);
            s1 += __shfl_xor(s1, m);
        }
        if (lane < deg) {
            sal[lane * NH + 2 * w]     = x0 / (s0 + 1e-16f);
            sal[lane * NH + 2 * w + 1] = x1 / (s1 + 1e-16f);
            if (w == 0) sidx[lane] = src;
        }
        __syncthreads();
        int j = 0;
        for (; j + 4 <= deg; j += 4) {            // 4 loads in flight
            int sj0 = sidx[j], sj1 = sidx[j + 1], sj2 = sidx[j + 2], sj3 = sidx[j + 3];
            float b0 = sal[j * NH + hd], b1 = sal[(j + 1) * NH + hd];
            float b2 = sal[(j + 2) * NH + hd], b3 = sal[(j + 3) * NH + hd];
            f16x2 v0 = *(const f16x2*)(h + (long)sj0 * HC2 + 2 * t);
            f16x2 v1 = *(const f16x2*)(h + (long)sj1 * HC2 + 2 * t);
            f16x2 v2 = *(const f16x2*)(h + (long)sj2 * HC2 + 2 * t);
            f16x2 v3 = *(const f16x2*)(h + (long)sj3 * HC2 + 2 * t);
            a0 += b0 * (float)v0[0] + b1 * (float)v1[0] + b2 * (float)v2[0] + b3 * (float)v3[0];
            a1 += b0 * (float)v0[1] + b1 * (float)v1[1] + b2 * (float)v2[1] + b3 * (float)v3[1];
        }
        for (; j < deg; j++) {
            int src2 = sidx[j];
            float a = sal[j * NH + hd];
            f16x2 v = *(const f16x2*)(h + (long)src2 * HC2 + 2 * t);
            a0 += a * (float)v[0];
            a1 += a * (float)v[1];
        }
    } else {
        float2 adv = *(const float2*)(ad + n * NH + 2 * w);
        float m0 = -1e30f, m1 = -1e30f;
        for (int j = lane; j < deg; j += 64) {
            float2 avv = *(const float2*)(as + (long)colidx[k0 + j] * NH + 2 * w);
            m0 = fmaxf(m0, leaky(avv.x + adv.x));
            m1 = fmaxf(m1, leaky(avv.y + adv.y));
        }
        for (int m = 32; m; m >>= 1) {
            m0 = fmaxf(m0, __shfl_xor(m0, m));
            m1 = fmaxf(m1, __shfl_xor(m1, m));
        }
        float s0 = 0.f, s1 = 0.f;
        for (int j = lane; j < deg; j += 64) {
            float2 avv = *(const float2*)(as + (long)colidx[k0 + j] * NH + 2 * w);
            s0 += __expf(leaky(avv.x + adv.x) - m0);
            s1 += __expf(leaky(avv.y + adv.y) - m1);
        }
        for (int m = 32; m; m >>= 1) {
            s0 += __shfl_xor(s0, m);
            s1 += __shfl_xor(s1, m);
        }
        float i0 = 1.f / (s0 + 1e-16f), i1 = 1.f / (s1 + 1e-16f);
        for (int c0 = 0; c0 < deg; c0 += 64) {
            int cn = min(64, deg - c0);
            __syncthreads();
            if (lane < cn) {
                int src = colidx[k0 + c0 + lane];
                float2 avv = *(const float2*)(as + (long)src * NH + 2 * w);
                sal[lane * NH + 2 * w]     = __expf(leaky(avv.x + adv.x) - m0) * i0;
                sal[lane * NH + 2 * w + 1] = __expf(leaky(avv.y + adv.y) - m1) * i1;
                if (w == 0) sidx[lane] = src;
            }
            __syncthreads();
            for (int j = 0; j < cn; j++) {
                int src2 = sidx[j];
                float a = sal[j * NH + hd];
                f16x2 v = *(const f16x2*)(h + (long)src2 * HC2 + 2 * t);
                a0 += a * (float)v[0];
                a1 += a * (float)v[1];
            }
        }
    }
    facc[2 * t] = a0;
    facc[2 * t + 1] = a1;
    __syncthreads();
    if (t < C2) {
        float s = 0.f;
#pragma unroll
        for (int hh = 0; hh < NH; hh++) s += facc[hh * C2 + t];
        s = s * 0.1f + bias[t];
        out[(long)n * C2 + t] = s > 0.f ? s : 0.f;
    }
}

// ---------------- host ----------------
extern "C" void kernel_launch(void* const* d_in, const int* in_sizes, int n_in,
                              void* d_out, int out_size, void* d_ws, size_t ws_size,
                              hipStream_t stream) {
    const float* x      = (const float*)d_in[0];
    const int*   ei     = (const int*)d_in[1];
    const float* W1     = (const float*)d_in[2];
    const float* asrc1  = (const float*)d_in[3];
    const float* adst1  = (const float*)d_in[4];
    const float* b1     = (const float*)d_in[5];
    const float* W2     = (const float*)d_in[6];
    const float* asrc2  = (const float*)d_in[7];
    const float* adst2  = (const float*)d_in[8];
    const float* b2     = (const float*)d_in[9];
    float* out = (float*)d_out;
    const int E  = in_sizes[1] / 2;
    const int EN = E + NN;

    char* base = (char*)d_ws;
    size_t o = 0;
    auto alloc = [&](size_t bytes) { size_t r = o; o += (bytes + 255) & ~(size_t)255; return r; };
    _Float16* A1    = (_Float16*)(base + alloc((size_t)MP * K1P * 2));
    _Float16* W1t   = (_Float16*)(base + alloc((size_t)HC1 * K1P * 2));
    _Float16* A2    = (_Float16*)(base + alloc((size_t)MP * HC1 * 2));
    _Float16* W2t   = (_Float16*)(base + alloc((size_t)HC2 * HC1 * 2));
    _Float16* h1pre = (_Float16*)(base + alloc((size_t)MP * HC1 * 2));
    _Float16* h2pre = (_Float16*)(base + alloc((size_t)MP * HC2 * 2));
    float* as1      = (float*)(base + alloc((size_t)NN * NH * 4));
    float* ad1      = (float*)(base + alloc((size_t)NN * NH * 4));
    float* as2      = (float*)(base + alloc((size_t)NN * NH * 4));
    float* ad2      = (float*)(base + alloc((size_t)NN * NH * 4));
    int* counts     = (int*)(base + alloc((size_t)(NN + 1) * 4));
    int* rowptr     = (int*)(base + alloc((size_t)(NN + 1) * 4));
    int* cursor     = (int*)(base + alloc((size_t)(NN + 1) * 4));
    int* colidx     = (int*)(base + alloc((size_t)EN * 4));
    (void)ws_size; (void)n_in; (void)out_size;

    const int NCNT = (E + 255) / 256;
    const int FILLB = (EN + 255) / 256;
    const int G1 = 8 * (MP / 256 / 8) * (HC1 / 128);   // 400 gemm1 blocks
    const int G2 = 8 * (MP / 128 / 8) * (HC2 / 128);   // 400 gemm2 blocks (MFRAG=4)

    // ---- zero counts, then fused prep (cast + both transposes + edge count) ----
    hipMemsetAsync(counts, 0, (size_t)(NN + 1) * 4, stream);
    k_prep<<<NCAST + NW1 + NW2 + NCNT, 256, 0, stream>>>(x, A1, W1, W1t, W2, W2t, ei, counts, E);
    // ---- CSR scan (rowptr/cursor) ----
    k_scan<<<1, 1024, 0, stream>>>(counts, rowptr, cursor, NN);
    // ---- layer 1 GEMM (+ fused logits) with CSR-fill side-job blocks ----
    k_gemm<8><<<G1 + FILLB, 256, 0, stream>>>(A1, W1t, h1pre, K1P, HC1, HC1 / 128,
                                              asrc1, adst1, as1, ad1, C1,
                                              G1, ei, cursor, colidx, E);
    // ---- layer 1: fused softmax/aggregate -> A2 (pad rows zeroed inside) ----
    k_agg1<<<MP, 320, 0, stream>>>(rowptr, colidx, as1, ad1, h1pre, b1, A2);
    // ---- layer 2 GEMM (+ fused logits), BM=128 for 400 blocks ----
    k_gemm<4><<<G2, 256, 0, stream>>>(A2, W2t, h2pre, HC1, HC2, HC2 / 128,
                                      asrc2, adst2, as2, ad2, C2,
                                      G2, ei, cursor, colidx, E);
    // ---- layer 2: fused softmax/aggregate + head mean ----
    k_agg2<<<NN, 320, 0, stream>>>(rowptr, colidx, as2, ad2, h2pre, b2, out);
}